// Round 1
// baseline (409.819 us; speedup 1.0000x reference)
//
#include <hip/hip_runtime.h>
#include <math.h>

#define BN_EPS 1e-5f
constexpr int CAP = 64;     // max neighbors/node incl self-loop; deg~Poisson(16), P(>63)~0
constexpr int BSH = 9;      // dst-bucket shift: 512 nodes / bucket
constexpr int BCAP = 10240; // entries per bucket (avg 8192, sd ~90; +22 sigma)

typedef __attribute__((ext_vector_type(8))) short bf16x8;
typedef __attribute__((ext_vector_type(4))) float f32x4;

// ---- bf16 helpers (round-to-nearest-even) ----
__device__ inline unsigned short f2bf(float f) {
    unsigned u = __float_as_uint(f);
    unsigned r = (u + 0x7fffu + ((u >> 16) & 1u)) >> 16;
    return (unsigned short)r;
}
__device__ inline float2 bf2_to_f2(unsigned int v) {
    float2 r;
    r.x = __uint_as_float(v << 16);
    r.y = __uint_as_float(v & 0xffff0000u);
    return r;
}
__device__ inline void addv(float* a, uint4 v) {
    float2 x0 = bf2_to_f2(v.x), x1 = bf2_to_f2(v.y), x2 = bf2_to_f2(v.z), x3 = bf2_to_f2(v.w);
    a[0] += x0.x; a[1] += x0.y; a[2] += x1.x; a[3] += x1.y;
    a[4] += x2.x; a[5] += x2.y; a[6] += x3.x; a[7] += x3.y;
}

// ---------------- graph build: 2-phase dst-binned counting sort ----------------
__global__ __launch_bounds__(256) void k_zero(int* __restrict__ buf, int L) {
    int i = blockIdx.x * 256 + threadIdx.x;
    if (i < L) buf[i] = 0;
}

__global__ __launch_bounds__(256) void k_bin(const int* __restrict__ ei, int E, int K,
                                             uint2* __restrict__ bins, int* __restrict__ bcnt) {
    __shared__ int hist[256];
    __shared__ int lbase[256];
    const int tid = threadIdx.x;
    const int e0 = blockIdx.x * 2048;
    hist[tid] = 0;
    __syncthreads();

    int s[8], d[8];
    bool m[8];
#pragma unroll
    for (int i = 0; i < 8; ++i) {
        int e = e0 + i * 256 + tid;
        m[i] = e < E;
        s[i] = m[i] ? ei[e] : 0;
        d[i] = m[i] ? ei[E + e] : 0;
        if (m[i]) atomicAdd(&hist[d[i] >> BSH], 1);
    }
    __syncthreads();
    if (tid < K && hist[tid] > 0) lbase[tid] = atomicAdd(&bcnt[tid], hist[tid]);
    __syncthreads();
    hist[tid] = 0;
    __syncthreads();
#pragma unroll
    for (int i = 0; i < 8; ++i) {
        if (m[i]) {
            int b = d[i] >> BSH;
            int pos = lbase[b] + atomicAdd(&hist[b], 1);
            if (pos < BCAP) bins[(size_t)b * BCAP + pos] = make_uint2((unsigned)s[i], (unsigned)d[i]);
        }
    }
}

__global__ __launch_bounds__(1024) void k_place(const uint2* __restrict__ bins,
                                                const int* __restrict__ bcnt,
                                                int* __restrict__ col, int* __restrict__ cnt,
                                                float* __restrict__ dinv, int* __restrict__ dhist,
                                                int N) {
    const int b = blockIdx.x;
    const int node0 = b << BSH;
    const int nn = min(1 << BSH, N - node0);
    __shared__ int c2[1 << BSH];
    __shared__ int lh[CAP + 2];
    const int tid = threadIdx.x;
    if (tid < CAP + 2) lh[tid] = 0;
    for (int i = tid; i < nn; i += 1024) {
        c2[i] = 1;
        col[(size_t)(node0 + i) * CAP] = node0 + i;
    }
    __syncthreads();
    const int nb = min(bcnt[b], BCAP);
    const uint2* __restrict__ bb = bins + (size_t)b * BCAP;
    for (int i = tid; i < nb; i += 1024) {
        uint2 e = bb[i];
        int pos = atomicAdd(&c2[(int)e.y - node0], 1);
        if (pos < CAP) col[(size_t)e.y * CAP + pos] = (int)e.x;
    }
    __syncthreads();
    for (int i = tid; i < nn; i += 1024) {
        int c = c2[i];
        cnt[node0 + i] = c;
        dinv[node0 + i] = rsqrtf((float)c);
        atomicAdd(&lh[min(c, CAP)], 1);
    }
    __syncthreads();
    if (tid <= CAP && lh[tid] > 0) atomicAdd(&dhist[tid], lh[tid]);
}

// sort each node's neighbor list ascending by src id.
// Concurrent waves walk their (equal-length, degree-matched) lists in lockstep, so the
// p-th sorted neighbor of all co-resident nodes lands in a sliding ~5MB window of the
// h-table -> per-XCD L2 (4MB) captures the gather working set instead of random misses.
__global__ __launch_bounds__(256) void k_sortcol(int* __restrict__ col,
                                                 const int* __restrict__ cnt, int N) {
    constexpr int SB = 240;              // nodes per block; LDS = 240*65*4 = 62.4KB
    __shared__ int ls[SB * 65];          // row stride 65: bank = (t + i) % 32, conflict-free
    __shared__ int lcnt[SB];
    const int tid = threadIdx.x;
    const int node0 = blockIdx.x * SB;
    const int nn = min(SB, N - node0);
    for (int i = tid; i < nn; i += 256) lcnt[i] = min(cnt[node0 + i], CAP);
    __syncthreads();
    // stage-in: only used chunks (ceil(n/4) int4 per node), coalesced
    for (int idx = tid; idx < nn * 16; idx += 256) {
        int nd = idx >> 4, c4 = (idx & 15) * 4;
        if (c4 < lcnt[nd]) {
            int4 v = *(const int4*)(col + (size_t)(node0 + nd) * CAP + c4);
            int* dst = &ls[nd * 65 + c4];
            dst[0] = v.x; dst[1] = v.y; dst[2] = v.z; dst[3] = v.w;
        }
    }
    __syncthreads();
    // per-thread insertion sort (n ~ 17 avg -> ~145 steps)
    if (tid < nn) {
        int n = lcnt[tid];
        int* a = &ls[tid * 65];
        for (int i = 1; i < n; ++i) {
            int key = a[i];
            int j = i - 1;
            while (j >= 0 && a[j] > key) { a[j + 1] = a[j]; --j; }
            a[j + 1] = key;
        }
    }
    __syncthreads();
    // stage-out
    for (int idx = tid; idx < nn * 16; idx += 256) {
        int nd = idx >> 4, c4 = (idx & 15) * 4;
        if (c4 < lcnt[nd]) {
            const int* src = &ls[nd * 65 + c4];
            *(int4*)(col + (size_t)(node0 + nd) * CAP + c4) = make_int4(src[0], src[1], src[2], src[3]);
        }
    }
}

// exclusive prefix over degree histogram, DESCENDING degree -> heavy blocks launch first
__global__ void k_prefix(const int* __restrict__ dhist, int* __restrict__ doff) {
    if (threadIdx.x == 0) {
        int s = 0;
        for (int b = CAP; b >= 0; --b) { doff[b] = s; s += dhist[b]; }
    }
}

// scatter node ids into degree-sorted permutation
__global__ __launch_bounds__(256) void k_scatter(const int* __restrict__ cnt, int* __restrict__ doff,
                                                 int* __restrict__ perm, int N) {
    __shared__ int lh[CAP + 2];
    __shared__ int lbase[CAP + 2];
    __shared__ int lpos[CAP + 2];
    const int tid = threadIdx.x;
    if (tid < CAP + 2) { lh[tid] = 0; lpos[tid] = 0; }
    __syncthreads();
    const int i = blockIdx.x * 256 + tid;
    const bool act = i < N;
    int b = 0;
    if (act) { b = min(cnt[i], CAP); atomicAdd(&lh[b], 1); }
    __syncthreads();
    if (tid <= CAP && lh[tid] > 0) lbase[tid] = atomicAdd(&doff[tid], lh[tid]);
    __syncthreads();
    if (act) {
        int p = atomicAdd(&lpos[b], 1);
        perm[lbase[b] + p] = i;
    }
}

// ---------------- weight repack: fp32 [FIN][FOUT] -> bf16 fragment-linear ----------------
__global__ __launch_bounds__(256) void k_repack(
    const float* __restrict__ w_in, const float* __restrict__ w1,
    const float* __restrict__ w2, const float* __restrict__ w3,
    unsigned short* __restrict__ f_in, unsigned short* __restrict__ f1,
    unsigned short* __restrict__ f2, unsigned short* __restrict__ f3)
{
    int idx = blockIdx.x * 256 + threadIdx.x;  // 0..40959
    const float* src;
    unsigned short* dst;
    int FOUT, local;
    if (idx < 8192)       { src = w_in; dst = f_in; FOUT = 64;  local = idx; }
    else if (idx < 16384) { src = w1;   dst = f1;   FOUT = 128; local = idx - 8192; }
    else if (idx < 32768) { src = w2;   dst = f2;   FOUT = 128; local = idx - 16384; }
    else                  { src = w3;   dst = f3;   FOUT = 64;  local = idx - 32768; }
    int k = local / FOUT, n = local % FOUT;
    int NT = FOUT >> 4;
    dst[((((k >> 5) * NT + (n >> 4)) * 64) + ((k >> 3) & 3) * 16 + (n & 15)) * 8 + (k & 7)] = f2bf(src[local]);
}

// ---------------- layer 0: h0 = bf16( dinv * relu(x @ w_in + b_in) ) ----------------
__global__ __launch_bounds__(256) void mfma_gemm0(
    const float* __restrict__ in, const unsigned short* __restrict__ wfrag,
    const float* __restrict__ bias, const float* __restrict__ rowscale,
    unsigned short* __restrict__ out, int N)
{
    constexpr int FIN = 128, FOUT = 64, KS = 4, NT = 4, OST = 72;
    __shared__ unsigned short otile[4 * 16 * OST];
    __shared__ float ct[FOUT];
    const int tid = threadIdx.x;
    if (tid < FOUT) ct[tid] = bias[tid];
    __syncthreads();

    const int wid = tid >> 6, lane = tid & 63;
    const int q = lane >> 4, m = lane & 15;
    const int rowbase = blockIdx.x * 64 + wid * 16;
    const int rowc = min(rowbase + m, N - 1);
    const bf16x8* __restrict__ wf = (const bf16x8*)wfrag;

    f32x4 accm[NT];
#pragma unroll
    for (int nt = 0; nt < NT; ++nt) accm[nt] = (f32x4){0.f, 0.f, 0.f, 0.f};

#pragma unroll
    for (int ks = 0; ks < KS; ++ks) {
        const float* ap = in + (size_t)rowc * FIN + ks * 32 + q * 8;
        float4 a0 = *(const float4*)ap;
        float4 a1 = *(const float4*)(ap + 4);
        bf16x8 af;
        af[0] = (short)f2bf(a0.x); af[1] = (short)f2bf(a0.y);
        af[2] = (short)f2bf(a0.z); af[3] = (short)f2bf(a0.w);
        af[4] = (short)f2bf(a1.x); af[5] = (short)f2bf(a1.y);
        af[6] = (short)f2bf(a1.z); af[7] = (short)f2bf(a1.w);
#pragma unroll
        for (int nt = 0; nt < NT; ++nt)
            accm[nt] = __builtin_amdgcn_mfma_f32_16x16x32_bf16(af, wf[(ks * NT + nt) * 64 + lane], accm[nt], 0, 0, 0);
    }

    unsigned short* ot = otile + wid * 16 * OST;
    float rs[4];
#pragma unroll
    for (int r = 0; r < 4; ++r) rs[r] = rowscale[min(rowbase + q * 4 + r, N - 1)];
#pragma unroll
    for (int nt = 0; nt < NT; ++nt) {
        int c = nt * 16 + m;
        float t = ct[c];
#pragma unroll
        for (int r = 0; r < 4; ++r) {
            float z = fmaxf(accm[nt][r] + t, 0.f);
            ot[(q * 4 + r) * OST + c] = f2bf(z * rs[r]);
        }
    }
#pragma unroll
    for (int idx = lane; idx < 16 * (FOUT / 8); idx += 64) {
        int rrow = idx >> 3, cc = idx & 7;
        int gr = rowbase + rrow;
        if (gr < N)
            *(uint4*)(out + (size_t)gr * FOUT + cc * 8) = *(const uint4*)&ot[rrow * OST + cc * 8];
    }
}

// ---------------- layer 1: h1 = bf16( dinv * relu(bn1( (A_hat@h0) @ w1 + b1 )) ) ----------------
// Gather-in-fragment, degree-equalized, 8-neighbor batches (16 uint4 in flight).
__global__ __launch_bounds__(256) void agg_mfma1(
    const unsigned short* __restrict__ hin, const unsigned short* __restrict__ wfrag,
    const float* __restrict__ bias, const float* __restrict__ g, const float* __restrict__ beta,
    const float* __restrict__ mm, const float* __restrict__ vv,
    const int* __restrict__ col, const int* __restrict__ cnt, const float* __restrict__ dinv,
    const int* __restrict__ perm,
    unsigned short* __restrict__ out, int N)
{
    constexpr int FIN = 64, FOUT = 128, KS = 2, NT = 8, OST = 136;
    __shared__ unsigned short otile[4 * 16 * OST];
    __shared__ float cs[FOUT], ct[FOUT];
    __shared__ int lperm[64];
    const int tid = threadIdx.x;
    if (tid < FOUT) {
        float s = g[tid] * rsqrtf(vv[tid] + BN_EPS);
        cs[tid] = s;
        ct[tid] = bias[tid] * s + beta[tid] - mm[tid] * s;
    }
    if (tid < 64) lperm[tid] = perm[min((int)(blockIdx.x * 64 + tid), N - 1)];
    __syncthreads();

    const int wid = tid >> 6, lane = tid & 63;
    const int q = lane >> 4, m = lane & 15;
    const int rowbase = blockIdx.x * 64 + wid * 16;
    const int node = lperm[wid * 16 + m];
    const int n = (rowbase + m < N) ? min(cnt[node], CAP) : 0;
    const int* __restrict__ c = col + (size_t)node * CAP;

    float acc[KS][8];
#pragma unroll
    for (int i = 0; i < KS; ++i)
#pragma unroll
        for (int e = 0; e < 8; ++e) acc[i][e] = 0.f;

    int p = 0;
    for (; p + 8 <= n; p += 8) {
        int4 ca = *(const int4*)(c + p);
        int4 cb = *(const int4*)(c + p + 4);
        const unsigned short* r0 = hin + (size_t)ca.x * FIN + q * 8;
        const unsigned short* r1 = hin + (size_t)ca.y * FIN + q * 8;
        const unsigned short* r2 = hin + (size_t)ca.z * FIN + q * 8;
        const unsigned short* r3 = hin + (size_t)ca.w * FIN + q * 8;
        const unsigned short* r4 = hin + (size_t)cb.x * FIN + q * 8;
        const unsigned short* r5 = hin + (size_t)cb.y * FIN + q * 8;
        const unsigned short* r6 = hin + (size_t)cb.z * FIN + q * 8;
        const unsigned short* r7 = hin + (size_t)cb.w * FIN + q * 8;
        uint4 v0a = *(const uint4*)r0, v0b = *(const uint4*)(r0 + 32);
        uint4 v1a = *(const uint4*)r1, v1b = *(const uint4*)(r1 + 32);
        uint4 v2a = *(const uint4*)r2, v2b = *(const uint4*)(r2 + 32);
        uint4 v3a = *(const uint4*)r3, v3b = *(const uint4*)(r3 + 32);
        uint4 v4a = *(const uint4*)r4, v4b = *(const uint4*)(r4 + 32);
        uint4 v5a = *(const uint4*)r5, v5b = *(const uint4*)(r5 + 32);
        uint4 v6a = *(const uint4*)r6, v6b = *(const uint4*)(r6 + 32);
        uint4 v7a = *(const uint4*)r7, v7b = *(const uint4*)(r7 + 32);
        addv(acc[0], v0a); addv(acc[1], v0b);
        addv(acc[0], v1a); addv(acc[1], v1b);
        addv(acc[0], v2a); addv(acc[1], v2b);
        addv(acc[0], v3a); addv(acc[1], v3b);
        addv(acc[0], v4a); addv(acc[1], v4b);
        addv(acc[0], v5a); addv(acc[1], v5b);
        addv(acc[0], v6a); addv(acc[1], v6b);
        addv(acc[0], v7a); addv(acc[1], v7b);
    }
    for (; p + 4 <= n; p += 4) {
        int4 ca = *(const int4*)(c + p);
        const unsigned short* r0 = hin + (size_t)ca.x * FIN + q * 8;
        const unsigned short* r1 = hin + (size_t)ca.y * FIN + q * 8;
        const unsigned short* r2 = hin + (size_t)ca.z * FIN + q * 8;
        const unsigned short* r3 = hin + (size_t)ca.w * FIN + q * 8;
        uint4 v0a = *(const uint4*)r0, v0b = *(const uint4*)(r0 + 32);
        uint4 v1a = *(const uint4*)r1, v1b = *(const uint4*)(r1 + 32);
        uint4 v2a = *(const uint4*)r2, v2b = *(const uint4*)(r2 + 32);
        uint4 v3a = *(const uint4*)r3, v3b = *(const uint4*)(r3 + 32);
        addv(acc[0], v0a); addv(acc[1], v0b);
        addv(acc[0], v1a); addv(acc[1], v1b);
        addv(acc[0], v2a); addv(acc[1], v2b);
        addv(acc[0], v3a); addv(acc[1], v3b);
    }
    for (; p < n; ++p) {
        const unsigned short* r0 = hin + (size_t)c[p] * FIN + q * 8;
        addv(acc[0], *(const uint4*)r0);
        addv(acc[1], *(const uint4*)(r0 + 32));
    }

    const float di = dinv[node];
    bf16x8 af[KS];
#pragma unroll
    for (int i = 0; i < KS; ++i)
#pragma unroll
        for (int e = 0; e < 8; ++e) af[i][e] = (short)f2bf(acc[i][e] * di);

    f32x4 accm[NT];
#pragma unroll
    for (int nt = 0; nt < NT; ++nt) accm[nt] = (f32x4){0.f, 0.f, 0.f, 0.f};
    const bf16x8* __restrict__ wf = (const bf16x8*)wfrag;
#pragma unroll
    for (int ks = 0; ks < KS; ++ks)
#pragma unroll
        for (int nt = 0; nt < NT; ++nt)
            accm[nt] = __builtin_amdgcn_mfma_f32_16x16x32_bf16(af[ks], wf[(ks * NT + nt) * 64 + lane], accm[nt], 0, 0, 0);

    unsigned short* ot = otile + wid * 16 * OST;
    float rs[4];
#pragma unroll
    for (int r = 0; r < 4; ++r) rs[r] = dinv[lperm[wid * 16 + q * 4 + r]];
#pragma unroll
    for (int nt = 0; nt < NT; ++nt) {
        int cc = nt * 16 + m;
        float s = cs[cc], t = ct[cc];
#pragma unroll
        for (int r = 0; r < 4; ++r) {
            float z = fmaxf(accm[nt][r] * s + t, 0.f);
            ot[(q * 4 + r) * OST + cc] = f2bf(z * rs[r]);
        }
    }
#pragma unroll
    for (int idx = lane; idx < 16 * (FOUT / 8); idx += 64) {
        int rrow = idx >> 4, cc = idx & 15;
        if (rowbase + rrow < N) {
            int gr = lperm[wid * 16 + rrow];
            *(uint4*)(out + (size_t)gr * FOUT + cc * 8) = *(const uint4*)&ot[rrow * OST + cc * 8];
        }
    }
}

// ---------------- layers 2+3 fused: t3 = bf16( dinv * ( relu(bn2((A_hat@h1)@w2+b2)) @ w3 ) ) ----------------
// 4-neighbor gather batches (16 uint4 in flight).
__global__ __launch_bounds__(256) void agg_mfma23(
    const unsigned short* __restrict__ hin, const unsigned short* __restrict__ w2f,
    const float* __restrict__ b2, const float* __restrict__ g2, const float* __restrict__ beta2,
    const float* __restrict__ m2, const float* __restrict__ v2,
    const unsigned short* __restrict__ w3f,
    const int* __restrict__ col, const int* __restrict__ cnt, const float* __restrict__ dinv,
    const int* __restrict__ perm,
    unsigned short* __restrict__ out, int N)
{
    constexpr int FIN = 128, KS = 4, NT1 = 8, NT2 = 4, OST = 136, OST2 = 72;
    __shared__ unsigned short otile[4 * 16 * OST];
    __shared__ float cs[128], ct[128];
    __shared__ int lperm[64];
    const int tid = threadIdx.x;
    if (tid < 128) {
        float s = g2[tid] * rsqrtf(v2[tid] + BN_EPS);
        cs[tid] = s;
        ct[tid] = b2[tid] * s + beta2[tid] - m2[tid] * s;
    }
    if (tid < 64) lperm[tid] = perm[min((int)(blockIdx.x * 64 + tid), N - 1)];
    __syncthreads();

    const int wid = tid >> 6, lane = tid & 63;
    const int q = lane >> 4, m = lane & 15;
    const int rowbase = blockIdx.x * 64 + wid * 16;
    const int node = lperm[wid * 16 + m];
    const int n = (rowbase + m < N) ? min(cnt[node], CAP) : 0;
    const int* __restrict__ c = col + (size_t)node * CAP;

    float acc[KS][8];
#pragma unroll
    for (int i = 0; i < KS; ++i)
#pragma unroll
        for (int e = 0; e < 8; ++e) acc[i][e] = 0.f;

    int p = 0;
    for (; p + 4 <= n; p += 4) {
        int4 ca = *(const int4*)(c + p);
        const unsigned short* r0 = hin + (size_t)ca.x * FIN + q * 8;
        const unsigned short* r1 = hin + (size_t)ca.y * FIN + q * 8;
        const unsigned short* r2 = hin + (size_t)ca.z * FIN + q * 8;
        const unsigned short* r3 = hin + (size_t)ca.w * FIN + q * 8;
        uint4 v0[KS], v1[KS], v2[KS], v3[KS];
#pragma unroll
        for (int i = 0; i < KS; ++i) v0[i] = *(const uint4*)(r0 + i * 32);
#pragma unroll
        for (int i = 0; i < KS; ++i) v1[i] = *(const uint4*)(r1 + i * 32);
#pragma unroll
        for (int i = 0; i < KS; ++i) v2[i] = *(const uint4*)(r2 + i * 32);
#pragma unroll
        for (int i = 0; i < KS; ++i) v3[i] = *(const uint4*)(r3 + i * 32);
#pragma unroll
        for (int i = 0; i < KS; ++i) addv(acc[i], v0[i]);
#pragma unroll
        for (int i = 0; i < KS; ++i) addv(acc[i], v1[i]);
#pragma unroll
        for (int i = 0; i < KS; ++i) addv(acc[i], v2[i]);
#pragma unroll
        for (int i = 0; i < KS; ++i) addv(acc[i], v3[i]);
    }
    for (; p < n; ++p) {
        const unsigned short* r0 = hin + (size_t)c[p] * FIN + q * 8;
#pragma unroll
        for (int i = 0; i < KS; ++i) addv(acc[i], *(const uint4*)(r0 + i * 32));
    }

    const float di = dinv[node];
    bf16x8 af[KS];
#pragma unroll
    for (int i = 0; i < KS; ++i)
#pragma unroll
        for (int e = 0; e < 8; ++e) af[i][e] = (short)f2bf(acc[i][e] * di);

    // MFMA1: z2 = a2 @ w2
    f32x4 accm[NT1];
#pragma unroll
    for (int nt = 0; nt < NT1; ++nt) accm[nt] = (f32x4){0.f, 0.f, 0.f, 0.f};
    const bf16x8* __restrict__ wf2 = (const bf16x8*)w2f;
#pragma unroll
    for (int ks = 0; ks < KS; ++ks)
#pragma unroll
        for (int nt = 0; nt < NT1; ++nt)
            accm[nt] = __builtin_amdgcn_mfma_f32_16x16x32_bf16(af[ks], wf2[(ks * NT1 + nt) * 64 + lane], accm[nt], 0, 0, 0);

    // h2 = relu(bn2(z2)) -> per-wave LDS tile (C-layout rows -> A-frag reads)
    unsigned short* ot = otile + wid * 16 * OST;
#pragma unroll
    for (int nt = 0; nt < NT1; ++nt) {
        int cc = nt * 16 + m;
        float s = cs[cc], t = ct[cc];
#pragma unroll
        for (int r = 0; r < 4; ++r) {
            float z = fmaxf(accm[nt][r] * s + t, 0.f);
            ot[(q * 4 + r) * OST + cc] = f2bf(z);
        }
    }
    bf16x8 af2[KS];
#pragma unroll
    for (int ks = 0; ks < KS; ++ks)
        af2[ks] = *(const bf16x8*)&ot[m * OST + ks * 32 + q * 8];

    // MFMA2: t3 = h2 @ w3
    f32x4 acc2[NT2];
#pragma unroll
    for (int nt = 0; nt < NT2; ++nt) acc2[nt] = (f32x4){0.f, 0.f, 0.f, 0.f};
    const bf16x8* __restrict__ wf3 = (const bf16x8*)w3f;
#pragma unroll
    for (int ks = 0; ks < KS; ++ks)
#pragma unroll
        for (int nt = 0; nt < NT2; ++nt)
            acc2[nt] = __builtin_amdgcn_mfma_f32_16x16x32_bf16(af2[ks], wf3[(ks * NT2 + nt) * 64 + lane], acc2[nt], 0, 0, 0);

    float rs[4];
#pragma unroll
    for (int r = 0; r < 4; ++r) rs[r] = dinv[lperm[wid * 16 + q * 4 + r]];
#pragma unroll
    for (int nt = 0; nt < NT2; ++nt) {
        int cc = nt * 16 + m;
#pragma unroll
        for (int r = 0; r < 4; ++r)
            ot[(q * 4 + r) * OST2 + cc] = f2bf(acc2[nt][r] * rs[r]);
    }
#pragma unroll
    for (int idx = lane; idx < 16 * 8; idx += 64) {
        int rrow = idx >> 3, cc = idx & 7;
        if (rowbase + rrow < N) {
            int gr = lperm[wid * 16 + rrow];
            *(uint4*)(out + (size_t)gr * 64 + cc * 8) = *(const uint4*)&ot[rrow * OST2 + cc * 8];
        }
    }
}

// ---------------- layer 3 tail fused: out = log_softmax( relu(bn3(A_hat@t3 + b3)) @ w_out + b_out ) ----------------
__global__ __launch_bounds__(256) void agg_final(
    const unsigned short* __restrict__ hin,
    const int* __restrict__ col, const int* __restrict__ cnt, const float* __restrict__ dinv,
    const int* __restrict__ perm,
    const float* __restrict__ b3, const float* __restrict__ g3, const float* __restrict__ beta3,
    const float* __restrict__ m3, const float* __restrict__ v3,
    const float* __restrict__ w_out, const float* __restrict__ b_out,
    float* __restrict__ out, int N)
{
    __shared__ float S[64], T[64], sw[64 * 8], sb[8];
    __shared__ int lperm[64];
    const int tid = threadIdx.x;
    if (tid < 64) {
        float s = g3[tid] * rsqrtf(v3[tid] + BN_EPS);
        S[tid] = s;
        T[tid] = b3[tid] * s + beta3[tid] - m3[tid] * s;
        lperm[tid] = perm[min((int)(blockIdx.x * 64 + tid), N - 1)];
    }
    if (tid < 8) sb[tid] = b_out[tid];
    sw[tid] = w_out[tid];
    sw[tid + 256] = w_out[tid + 256];
    __syncthreads();

    const int wid = tid >> 6, lane = tid & 63;
    const int q = lane >> 4, m = lane & 15;
    const int rowbase = blockIdx.x * 64 + wid * 16;
    const int node = lperm[wid * 16 + m];
    const int n = (rowbase + m < N) ? min(cnt[node], CAP) : 0;
    const int* __restrict__ c = col + (size_t)node * CAP;

    float acc[2][8];
#pragma unroll
    for (int i = 0; i < 2; ++i)
#pragma unroll
        for (int e = 0; e < 8; ++e) acc[i][e] = 0.f;

    int p = 0;
    for (; p + 8 <= n; p += 8) {
        int4 ca = *(const int4*)(c + p);
        int4 cb = *(const int4*)(c + p + 4);
        const unsigned short* r0 = hin + (size_t)ca.x * 64 + q * 8;
        const unsigned short* r1 = hin + (size_t)ca.y * 64 + q * 8;
        const unsigned short* r2 = hin + (size_t)ca.z * 64 + q * 8;
        const unsigned short* r3 = hin + (size_t)ca.w * 64 + q * 8;
        const unsigned short* r4 = hin + (size_t)cb.x * 64 + q * 8;
        const unsigned short* r5 = hin + (size_t)cb.y * 64 + q * 8;
        const unsigned short* r6 = hin + (size_t)cb.z * 64 + q * 8;
        const unsigned short* r7 = hin + (size_t)cb.w * 64 + q * 8;
        uint4 v0a = *(const uint4*)r0, v0b = *(const uint4*)(r0 + 32);
        uint4 v1a = *(const uint4*)r1, v1b = *(const uint4*)(r1 + 32);
        uint4 v2a = *(const uint4*)r2, v2b = *(const uint4*)(r2 + 32);
        uint4 v3a = *(const uint4*)r3, v3b = *(const uint4*)(r3 + 32);
        uint4 v4a = *(const uint4*)r4, v4b = *(const uint4*)(r4 + 32);
        uint4 v5a = *(const uint4*)r5, v5b = *(const uint4*)(r5 + 32);
        uint4 v6a = *(const uint4*)r6, v6b = *(const uint4*)(r6 + 32);
        uint4 v7a = *(const uint4*)r7, v7b = *(const uint4*)(r7 + 32);
        addv(acc[0], v0a); addv(acc[1], v0b);
        addv(acc[0], v1a); addv(acc[1], v1b);
        addv(acc[0], v2a); addv(acc[1], v2b);
        addv(acc[0], v3a); addv(acc[1], v3b);
        addv(acc[0], v4a); addv(acc[1], v4b);
        addv(acc[0], v5a); addv(acc[1], v5b);
        addv(acc[0], v6a); addv(acc[1], v6b);
        addv(acc[0], v7a); addv(acc[1], v7b);
    }
    for (; p + 4 <= n; p += 4) {
        int4 ca = *(const int4*)(c + p);
        const unsigned short* r0 = hin + (size_t)ca.x * 64 + q * 8;
        const unsigned short* r1 = hin + (size_t)ca.y * 64 + q * 8;
        const unsigned short* r2 = hin + (size_t)ca.z * 64 + q * 8;
        const unsigned short* r3 = hin + (size_t)ca.w * 64 + q * 8;
        uint4 v0a = *(const uint4*)r0, v0b = *(const uint4*)(r0 + 32);
        uint4 v1a = *(const uint4*)r1, v1b = *(const uint4*)(r1 + 32);
        uint4 v2a = *(const uint4*)r2, v2b = *(const uint4*)(r2 + 32);
        uint4 v3a = *(const uint4*)r3, v3b = *(const uint4*)(r3 + 32);
        addv(acc[0], v0a); addv(acc[1], v0b);
        addv(acc[0], v1a); addv(acc[1], v1b);
        addv(acc[0], v2a); addv(acc[1], v2b);
        addv(acc[0], v3a); addv(acc[1], v3b);
    }
    for (; p < n; ++p) {
        const unsigned short* r0 = hin + (size_t)c[p] * 64 + q * 8;
        addv(acc[0], *(const uint4*)r0);
        addv(acc[1], *(const uint4*)(r0 + 32));
    }

    const float di = dinv[node];
    float lg[8];
#pragma unroll
    for (int cc = 0; cc < 8; ++cc) lg[cc] = 0.f;
#pragma unroll
    for (int i = 0; i < 2; ++i) {
        int fbase = i * 32 + q * 8;
#pragma unroll
        for (int j = 0; j < 8; ++j) {
            int f = fbase + j;
            float z = fmaxf((acc[i][j] * di) * S[f] + T[f], 0.f);
#pragma unroll
            for (int cc = 0; cc < 8; ++cc) lg[cc] += z * sw[f * 8 + cc];
        }
    }
#pragma unroll
    for (int cc = 0; cc < 8; ++cc) {
        lg[cc] += __shfl_xor(lg[cc], 16);
        lg[cc] += __shfl_xor(lg[cc], 32);
    }
    if (q == 0 && rowbase + m < N) {
#pragma unroll
        for (int cc = 0; cc < 8; ++cc) lg[cc] += sb[cc];
        float mx = lg[0];
#pragma unroll
        for (int cc = 1; cc < 8; ++cc) mx = fmaxf(mx, lg[cc]);
        float sum = 0.f;
#pragma unroll
        for (int cc = 0; cc < 8; ++cc) sum += expf(lg[cc] - mx);
        float lse = logf(sum) + mx;
        float4 o0 = {lg[0] - lse, lg[1] - lse, lg[2] - lse, lg[3] - lse};
        float4 o1 = {lg[4] - lse, lg[5] - lse, lg[6] - lse, lg[7] - lse};
        float4* op = (float4*)(out + (size_t)node * 8);
        op[0] = o0;
        op[1] = o1;
    }
}

extern "C" void kernel_launch(void* const* d_in, const int* in_sizes, int n_in,
                              void* d_out, int out_size, void* d_ws, size_t ws_size,
                              hipStream_t stream) {
    const float* x     = (const float*)d_in[0];
    const int*   ei    = (const int*)d_in[1];
    const float* w_in  = (const float*)d_in[2];
    const float* b_in  = (const float*)d_in[3];
    const float* w1    = (const float*)d_in[4];
    const float* b1    = (const float*)d_in[5];
    const float* w2    = (const float*)d_in[6];
    const float* b2    = (const float*)d_in[7];
    const float* w3    = (const float*)d_in[8];
    const float* b3    = (const float*)d_in[9];
    const float* w_o   = (const float*)d_in[10];
    const float* b_o   = (const float*)d_in[11];
    const float* g1    = (const float*)d_in[12];
    const float* be1   = (const float*)d_in[13];
    const float* m1    = (const float*)d_in[14];
    const float* v1    = (const float*)d_in[15];
    const float* g2    = (const float*)d_in[16];
    const float* be2   = (const float*)d_in[17];
    const float* m2    = (const float*)d_in[18];
    const float* v2    = (const float*)d_in[19];
    const float* g3    = (const float*)d_in[20];
    const float* be3   = (const float*)d_in[21];
    const float* m3    = (const float*)d_in[22];
    const float* v3    = (const float*)d_in[23];

    const int N = in_sizes[0] / 128;
    const int E = in_sizes[1] / 2;
    const int K = (N + (1 << BSH) - 1) >> BSH;

    char* p = (char*)d_ws;
    auto alloc = [&](size_t bytes) {
        void* r = (void*)p;
        p += (bytes + 255) & ~(size_t)255;
        return r;
    };
    int*            cnt  = (int*)alloc((size_t)N * 4);
    float*          dinv = (float*)alloc((size_t)N * 4);
    int*            zbuf = (int*)alloc(512 * 4);         // [0..255]=bcnt, [256..383]=dhist
    int*            doff = (int*)alloc(128 * 4);
    int*            perm = (int*)alloc((size_t)N * 4);
    int*            col  = (int*)alloc((size_t)N * CAP * 4);
    uint2*          bins = (uint2*)alloc((size_t)K * BCAP * 8);
    unsigned short* hbA  = (unsigned short*)alloc((size_t)N * 128 * 2);
    unsigned short* hbB  = (unsigned short*)alloc((size_t)N * 128 * 2);
    unsigned short* f_in = (unsigned short*)alloc(8192 * 2);
    unsigned short* f1   = (unsigned short*)alloc(8192 * 2);
    unsigned short* f2   = (unsigned short*)alloc(16384 * 2);
    unsigned short* f3   = (unsigned short*)alloc(8192 * 2);
    int* bcnt  = zbuf;
    int* dhist = zbuf + 256;

    const int gN  = (N + 255) / 256;
    const int gB1 = (E + 2047) / 2048;
    const int gM  = (N + 63) / 64;
    const int gS  = (N + 239) / 240;

    // graph build + neighbor-list sort + degree sort (descending) + weight repack
    k_zero<<<2, 256, 0, stream>>>(zbuf, 512);
    k_bin<<<gB1, 256, 0, stream>>>(ei, E, K, bins, bcnt);
    k_place<<<K, 1024, 0, stream>>>(bins, bcnt, col, cnt, dinv, dhist, N);
    k_sortcol<<<gS, 256, 0, stream>>>(col, cnt, N);
    k_prefix<<<1, 64, 0, stream>>>(dhist, doff);
    k_scatter<<<gN, 256, 0, stream>>>(cnt, doff, perm, N);
    k_repack<<<160, 256, 0, stream>>>(w_in, w1, w2, w3, f_in, f1, f2, f3);

    // h0 = bf16( dinv * relu(x @ w_in + b_in) )                     [N,64]  -> hbA
    mfma_gemm0<<<gM, 256, 0, stream>>>(x, f_in, b_in, dinv, hbA, N);
    // h1 = bf16( dinv * relu(bn1( (A_hat@h0) @ w1 + b1 )) )         [N,128] -> hbB
    agg_mfma1<<<gM, 256, 0, stream>>>(hbA, f1, b1, g1, be1, m1, v1, col, cnt, dinv, perm, hbB, N);
    // t3 = bf16( dinv * ( relu(bn2((A_hat@h1)@w2+b2)) @ w3 ) )      [N,64]  -> hbA
    agg_mfma23<<<gM, 256, 0, stream>>>(hbB, f2, b2, g2, be2, m2, v2, f3, col, cnt, dinv, perm, hbA, N);
    // out = log_softmax( relu(bn3(A_hat@t3 + b3)) @ w_out + b_out ) [N,8]
    agg_final<<<gM, 256, 0, stream>>>(hbA, col, cnt, dinv, perm, b3, g3, be3, m3, v3, w_o, b_o, (float*)d_out, N);
}

// Round 2
// 352.614 us; speedup vs baseline: 1.1622x; 1.1622x over previous
//
#include <hip/hip_runtime.h>
#include <math.h>

#define BN_EPS 1e-5f
constexpr int CAP = 64;     // max neighbors/node incl self-loop; deg~Poisson(16), P(>63)~0
constexpr int BSH = 9;      // dst-bucket shift: 512 nodes / bucket
constexpr int BCAP = 10240; // entries per bucket (avg 8192, sd ~90; +22 sigma)

typedef __attribute__((ext_vector_type(8))) short bf16x8;
typedef __attribute__((ext_vector_type(4))) float f32x4;

// ---- bf16 helpers (round-to-nearest-even) ----
__device__ inline unsigned short f2bf(float f) {
    unsigned u = __float_as_uint(f);
    unsigned r = (u + 0x7fffu + ((u >> 16) & 1u)) >> 16;
    return (unsigned short)r;
}
__device__ inline float2 bf2_to_f2(unsigned int v) {
    float2 r;
    r.x = __uint_as_float(v << 16);
    r.y = __uint_as_float(v & 0xffff0000u);
    return r;
}
__device__ inline void addv(float* a, uint4 v) {
    float2 x0 = bf2_to_f2(v.x), x1 = bf2_to_f2(v.y), x2 = bf2_to_f2(v.z), x3 = bf2_to_f2(v.w);
    a[0] += x0.x; a[1] += x0.y; a[2] += x1.x; a[3] += x1.y;
    a[4] += x2.x; a[5] += x2.y; a[6] += x3.x; a[7] += x3.y;
}

// ---------------- graph build: 2-phase dst-binned counting sort ----------------
__global__ __launch_bounds__(256) void k_zero(int* __restrict__ buf, int L) {
    int i = blockIdx.x * 256 + threadIdx.x;
    if (i < L) buf[i] = 0;
}

__global__ __launch_bounds__(256) void k_bin(const int* __restrict__ ei, int E, int K,
                                             uint2* __restrict__ bins, int* __restrict__ bcnt) {
    __shared__ int hist[256];
    __shared__ int lbase[256];
    const int tid = threadIdx.x;
    const int e0 = blockIdx.x * 2048;
    hist[tid] = 0;
    __syncthreads();

    int s[8], d[8];
    bool m[8];
#pragma unroll
    for (int i = 0; i < 8; ++i) {
        int e = e0 + i * 256 + tid;
        m[i] = e < E;
        s[i] = m[i] ? ei[e] : 0;
        d[i] = m[i] ? ei[E + e] : 0;
        if (m[i]) atomicAdd(&hist[d[i] >> BSH], 1);
    }
    __syncthreads();
    if (tid < K && hist[tid] > 0) lbase[tid] = atomicAdd(&bcnt[tid], hist[tid]);
    __syncthreads();
    hist[tid] = 0;
    __syncthreads();
#pragma unroll
    for (int i = 0; i < 8; ++i) {
        if (m[i]) {
            int b = d[i] >> BSH;
            int pos = lbase[b] + atomicAdd(&hist[b], 1);
            if (pos < BCAP) bins[(size_t)b * BCAP + pos] = make_uint2((unsigned)s[i], (unsigned)d[i]);
        }
    }
}

// 2-pass bucketed placement: neighbor lists come out grouped by src>>14 (16K-node
// windows ~= 4MB of the widest h-table ~= one XCD L2), giving the gather a sliding
// window for free. Also pads each list to a multiple of 4 with sentinel id N
// (tables carry a zeroed row N) so gather loops have no scalar tail.
__global__ __launch_bounds__(1024) void k_place(const uint2* __restrict__ bins,
                                                const int* __restrict__ bcnt,
                                                int* __restrict__ col, int* __restrict__ cnt,
                                                float* __restrict__ dinv, int* __restrict__ dhist,
                                                int N) {
    const int b = blockIdx.x;
    const int node0 = b << BSH;
    const int nn = min(1 << BSH, N - node0);
    __shared__ int c2[1 << BSH];
    __shared__ int bk[(1 << BSH) * 8];
    __shared__ int lh[CAP + 2];
    const int tid = threadIdx.x;
    if (tid < CAP + 2) lh[tid] = 0;
    for (int i = tid; i < nn * 8; i += 1024) bk[i] = 0;
    for (int i = tid; i < nn; i += 1024) col[(size_t)(node0 + i) * CAP] = node0 + i;
    __syncthreads();
    const int nb = min(bcnt[b], BCAP);
    const uint2* __restrict__ bb = bins + (size_t)b * BCAP;
    // pass 1: count per (dst, src-bucket)
    for (int i = tid; i < nb; i += 1024) {
        uint2 e = bb[i];
        int bu = min((int)(e.x >> 14), 7);
        atomicAdd(&bk[((int)e.y - node0) * 8 + bu], 1);
    }
    __syncthreads();
    // per-dst exclusive prefix (+1: self-loop at slot 0); bk becomes write cursors
    for (int i = tid; i < nn; i += 1024) {
        int s = 1;
#pragma unroll
        for (int u = 0; u < 8; ++u) { int t = bk[i * 8 + u]; bk[i * 8 + u] = s; s += t; }
        c2[i] = s;
    }
    __syncthreads();
    // pass 2: bucketed placement
    for (int i = tid; i < nb; i += 1024) {
        uint2 e = bb[i];
        int bu = min((int)(e.x >> 14), 7);
        int pos = atomicAdd(&bk[((int)e.y - node0) * 8 + bu], 1);
        if (pos < CAP) col[(size_t)e.y * CAP + pos] = (int)e.x;
    }
    __syncthreads();
    for (int i = tid; i < nn; i += 1024) {
        int c = c2[i];
        cnt[node0 + i] = c;
        dinv[node0 + i] = rsqrtf((float)c);
        int cc = min(c, CAP), c4 = (cc + 3) & ~3;
        for (int j = cc; j < c4; ++j) col[(size_t)(node0 + i) * CAP + j] = N;
        atomicAdd(&lh[min(c, CAP)], 1);
    }
    __syncthreads();
    if (tid <= CAP && lh[tid] > 0) atomicAdd(&dhist[tid], lh[tid]);
}

// zero the sentinel row N of both feature tables
__global__ void k_zrow(unsigned short* __restrict__ a, unsigned short* __restrict__ b, int N) {
    int t = threadIdx.x;  // 128
    if (t < 64) a[(size_t)N * 64 + t] = 0;
    b[(size_t)N * 128 + t] = 0;
}

// exclusive prefix over degree histogram, DESCENDING degree -> heavy blocks launch first
__global__ void k_prefix(const int* __restrict__ dhist, int* __restrict__ doff) {
    if (threadIdx.x == 0) {
        int s = 0;
        for (int b = CAP; b >= 0; --b) { doff[b] = s; s += dhist[b]; }
    }
}

// scatter node ids into degree-sorted permutation
__global__ __launch_bounds__(256) void k_scatter(const int* __restrict__ cnt, int* __restrict__ doff,
                                                 int* __restrict__ perm, int N) {
    __shared__ int lh[CAP + 2];
    __shared__ int lbase[CAP + 2];
    __shared__ int lpos[CAP + 2];
    const int tid = threadIdx.x;
    if (tid < CAP + 2) { lh[tid] = 0; lpos[tid] = 0; }
    __syncthreads();
    const int i = blockIdx.x * 256 + tid;
    const bool act = i < N;
    int b = 0;
    if (act) { b = min(cnt[i], CAP); atomicAdd(&lh[b], 1); }
    __syncthreads();
    if (tid <= CAP && lh[tid] > 0) lbase[tid] = atomicAdd(&doff[tid], lh[tid]);
    __syncthreads();
    if (act) {
        int p = atomicAdd(&lpos[b], 1);
        perm[lbase[b] + p] = i;
    }
}

// ---------------- weight repack: fp32 [FIN][FOUT] -> bf16 fragment-linear ----------------
__global__ __launch_bounds__(256) void k_repack(
    const float* __restrict__ w_in, const float* __restrict__ w1,
    const float* __restrict__ w2, const float* __restrict__ w3,
    unsigned short* __restrict__ f_in, unsigned short* __restrict__ f1,
    unsigned short* __restrict__ f2, unsigned short* __restrict__ f3)
{
    int idx = blockIdx.x * 256 + threadIdx.x;  // 0..40959
    const float* src;
    unsigned short* dst;
    int FOUT, local;
    if (idx < 8192)       { src = w_in; dst = f_in; FOUT = 64;  local = idx; }
    else if (idx < 16384) { src = w1;   dst = f1;   FOUT = 128; local = idx - 8192; }
    else if (idx < 32768) { src = w2;   dst = f2;   FOUT = 128; local = idx - 16384; }
    else                  { src = w3;   dst = f3;   FOUT = 64;  local = idx - 32768; }
    int k = local / FOUT, n = local % FOUT;
    int NT = FOUT >> 4;
    dst[((((k >> 5) * NT + (n >> 4)) * 64) + ((k >> 3) & 3) * 16 + (n & 15)) * 8 + (k & 7)] = f2bf(src[local]);
}

// ---------------- layer 0: h0 = bf16( dinv * relu(x @ w_in + b_in) ) ----------------
__global__ __launch_bounds__(256) void mfma_gemm0(
    const float* __restrict__ in, const unsigned short* __restrict__ wfrag,
    const float* __restrict__ bias, const float* __restrict__ rowscale,
    unsigned short* __restrict__ out, int N)
{
    constexpr int FIN = 128, FOUT = 64, KS = 4, NT = 4, OST = 72;
    __shared__ unsigned short otile[4 * 16 * OST];
    __shared__ float ct[FOUT];
    const int tid = threadIdx.x;
    if (tid < FOUT) ct[tid] = bias[tid];
    __syncthreads();

    const int wid = tid >> 6, lane = tid & 63;
    const int q = lane >> 4, m = lane & 15;
    const int rowbase = blockIdx.x * 64 + wid * 16;
    const int rowc = min(rowbase + m, N - 1);
    const bf16x8* __restrict__ wf = (const bf16x8*)wfrag;

    f32x4 accm[NT];
#pragma unroll
    for (int nt = 0; nt < NT; ++nt) accm[nt] = (f32x4){0.f, 0.f, 0.f, 0.f};

#pragma unroll
    for (int ks = 0; ks < KS; ++ks) {
        const float* ap = in + (size_t)rowc * FIN + ks * 32 + q * 8;
        float4 a0 = *(const float4*)ap;
        float4 a1 = *(const float4*)(ap + 4);
        bf16x8 af;
        af[0] = (short)f2bf(a0.x); af[1] = (short)f2bf(a0.y);
        af[2] = (short)f2bf(a0.z); af[3] = (short)f2bf(a0.w);
        af[4] = (short)f2bf(a1.x); af[5] = (short)f2bf(a1.y);
        af[6] = (short)f2bf(a1.z); af[7] = (short)f2bf(a1.w);
#pragma unroll
        for (int nt = 0; nt < NT; ++nt)
            accm[nt] = __builtin_amdgcn_mfma_f32_16x16x32_bf16(af, wf[(ks * NT + nt) * 64 + lane], accm[nt], 0, 0, 0);
    }

    unsigned short* ot = otile + wid * 16 * OST;
    float rs[4];
#pragma unroll
    for (int r = 0; r < 4; ++r) rs[r] = rowscale[min(rowbase + q * 4 + r, N - 1)];
#pragma unroll
    for (int nt = 0; nt < NT; ++nt) {
        int c = nt * 16 + m;
        float t = ct[c];
#pragma unroll
        for (int r = 0; r < 4; ++r) {
            float z = fmaxf(accm[nt][r] + t, 0.f);
            ot[(q * 4 + r) * OST + c] = f2bf(z * rs[r]);
        }
    }
#pragma unroll
    for (int idx = lane; idx < 16 * (FOUT / 8); idx += 64) {
        int rrow = idx >> 3, cc = idx & 7;
        int gr = rowbase + rrow;
        if (gr < N)
            *(uint4*)(out + (size_t)gr * FOUT + cc * 8) = *(const uint4*)&ot[rrow * OST + cc * 8];
    }
}

// ---------------- layer 1: h1 = bf16( dinv * relu(bn1( (A_hat@h0) @ w1 + b1 )) ) ----------------
// Single-wave blocks (16 nodes/wave) for residency; sentinel-padded uniform 8/4-batches,
// col prefetched one batch ahead.
__global__ __launch_bounds__(64) void agg_mfma1(
    const unsigned short* __restrict__ hin, const unsigned short* __restrict__ wfrag,
    const float* __restrict__ bias, const float* __restrict__ g, const float* __restrict__ beta,
    const float* __restrict__ mm, const float* __restrict__ vv,
    const int* __restrict__ col, const int* __restrict__ cnt, const float* __restrict__ dinv,
    const int* __restrict__ perm,
    unsigned short* __restrict__ out, int N)
{
    constexpr int FIN = 64, FOUT = 128, KS = 2, NT = 8, OST = 136;
    __shared__ unsigned short otile[16 * OST];
    __shared__ float cs[FOUT], ct[FOUT];
    __shared__ int lperm[16];
    const int tid = threadIdx.x;
    for (int k = tid; k < FOUT; k += 64) {
        float s = g[k] * rsqrtf(vv[k] + BN_EPS);
        cs[k] = s;
        ct[k] = bias[k] * s + beta[k] - mm[k] * s;
    }
    if (tid < 16) lperm[tid] = perm[min((int)(blockIdx.x * 16 + tid), N - 1)];
    __syncthreads();

    const int lane = tid;
    const int q = lane >> 4, m = lane & 15;
    const int rowbase = blockIdx.x * 16;
    const int node = lperm[m];
    const int n = (rowbase + m < N) ? min(cnt[node], CAP) : 0;
    const int np = (n + 3) & ~3;
    const int* __restrict__ c = col + (size_t)node * CAP;

    float acc[KS][8];
#pragma unroll
    for (int i = 0; i < KS; ++i)
#pragma unroll
        for (int e = 0; e < 8; ++e) acc[i][e] = 0.f;

    int4 ca = *(const int4*)c;
    int4 cb = *(const int4*)(c + 4);
    int p = 0;
    for (; p + 8 <= np; p += 8) {
        const int pn = min(p + 8, CAP - 8);
        int4 na = *(const int4*)(c + pn);
        int4 nb = *(const int4*)(c + pn + 4);
        const unsigned short* r0 = hin + (size_t)ca.x * FIN + q * 8;
        const unsigned short* r1 = hin + (size_t)ca.y * FIN + q * 8;
        const unsigned short* r2 = hin + (size_t)ca.z * FIN + q * 8;
        const unsigned short* r3 = hin + (size_t)ca.w * FIN + q * 8;
        const unsigned short* r4 = hin + (size_t)cb.x * FIN + q * 8;
        const unsigned short* r5 = hin + (size_t)cb.y * FIN + q * 8;
        const unsigned short* r6 = hin + (size_t)cb.z * FIN + q * 8;
        const unsigned short* r7 = hin + (size_t)cb.w * FIN + q * 8;
        uint4 v0a = *(const uint4*)r0, v0b = *(const uint4*)(r0 + 32);
        uint4 v1a = *(const uint4*)r1, v1b = *(const uint4*)(r1 + 32);
        uint4 v2a = *(const uint4*)r2, v2b = *(const uint4*)(r2 + 32);
        uint4 v3a = *(const uint4*)r3, v3b = *(const uint4*)(r3 + 32);
        uint4 v4a = *(const uint4*)r4, v4b = *(const uint4*)(r4 + 32);
        uint4 v5a = *(const uint4*)r5, v5b = *(const uint4*)(r5 + 32);
        uint4 v6a = *(const uint4*)r6, v6b = *(const uint4*)(r6 + 32);
        uint4 v7a = *(const uint4*)r7, v7b = *(const uint4*)(r7 + 32);
        addv(acc[0], v0a); addv(acc[1], v0b);
        addv(acc[0], v1a); addv(acc[1], v1b);
        addv(acc[0], v2a); addv(acc[1], v2b);
        addv(acc[0], v3a); addv(acc[1], v3b);
        addv(acc[0], v4a); addv(acc[1], v4b);
        addv(acc[0], v5a); addv(acc[1], v5b);
        addv(acc[0], v6a); addv(acc[1], v6b);
        addv(acc[0], v7a); addv(acc[1], v7b);
        ca = na; cb = nb;
    }
    if (p < np) {  // remaining 4 (sentinel-padded)
        const unsigned short* r0 = hin + (size_t)ca.x * FIN + q * 8;
        const unsigned short* r1 = hin + (size_t)ca.y * FIN + q * 8;
        const unsigned short* r2 = hin + (size_t)ca.z * FIN + q * 8;
        const unsigned short* r3 = hin + (size_t)ca.w * FIN + q * 8;
        uint4 v0a = *(const uint4*)r0, v0b = *(const uint4*)(r0 + 32);
        uint4 v1a = *(const uint4*)r1, v1b = *(const uint4*)(r1 + 32);
        uint4 v2a = *(const uint4*)r2, v2b = *(const uint4*)(r2 + 32);
        uint4 v3a = *(const uint4*)r3, v3b = *(const uint4*)(r3 + 32);
        addv(acc[0], v0a); addv(acc[1], v0b);
        addv(acc[0], v1a); addv(acc[1], v1b);
        addv(acc[0], v2a); addv(acc[1], v2b);
        addv(acc[0], v3a); addv(acc[1], v3b);
    }

    const float di = dinv[node];
    bf16x8 af[KS];
#pragma unroll
    for (int i = 0; i < KS; ++i)
#pragma unroll
        for (int e = 0; e < 8; ++e) af[i][e] = (short)f2bf(acc[i][e] * di);

    f32x4 accm[NT];
#pragma unroll
    for (int nt = 0; nt < NT; ++nt) accm[nt] = (f32x4){0.f, 0.f, 0.f, 0.f};
    const bf16x8* __restrict__ wf = (const bf16x8*)wfrag;
#pragma unroll
    for (int ks = 0; ks < KS; ++ks)
#pragma unroll
        for (int nt = 0; nt < NT; ++nt)
            accm[nt] = __builtin_amdgcn_mfma_f32_16x16x32_bf16(af[ks], wf[(ks * NT + nt) * 64 + lane], accm[nt], 0, 0, 0);

    unsigned short* ot = otile;
    float rs[4];
#pragma unroll
    for (int r = 0; r < 4; ++r) rs[r] = dinv[lperm[q * 4 + r]];
#pragma unroll
    for (int nt = 0; nt < NT; ++nt) {
        int cc = nt * 16 + m;
        float s = cs[cc], t = ct[cc];
#pragma unroll
        for (int r = 0; r < 4; ++r) {
            float z = fmaxf(accm[nt][r] * s + t, 0.f);
            ot[(q * 4 + r) * OST + cc] = f2bf(z * rs[r]);
        }
    }
#pragma unroll
    for (int idx = lane; idx < 16 * (FOUT / 8); idx += 64) {
        int rrow = idx >> 4, cc = idx & 15;
        if (rowbase + rrow < N) {
            int gr = lperm[rrow];
            *(uint4*)(out + (size_t)gr * FOUT + cc * 8) = *(const uint4*)&ot[rrow * OST + cc * 8];
        }
    }
}

// ---------------- layers 2+3 fused: t3 = bf16( dinv * ( relu(bn2((A_hat@h1)@w2+b2)) @ w3 ) ) ----------------
// Single-wave blocks; 4-neighbor sentinel-padded batches, col prefetched.
__global__ __launch_bounds__(64) void agg_mfma23(
    const unsigned short* __restrict__ hin, const unsigned short* __restrict__ w2f,
    const float* __restrict__ b2, const float* __restrict__ g2, const float* __restrict__ beta2,
    const float* __restrict__ m2, const float* __restrict__ v2,
    const unsigned short* __restrict__ w3f,
    const int* __restrict__ col, const int* __restrict__ cnt, const float* __restrict__ dinv,
    const int* __restrict__ perm,
    unsigned short* __restrict__ out, int N)
{
    constexpr int FIN = 128, KS = 4, NT1 = 8, NT2 = 4, OST = 136, OST2 = 72;
    __shared__ unsigned short otile[16 * OST];
    __shared__ float cs[128], ct[128];
    __shared__ int lperm[16];
    const int tid = threadIdx.x;
    for (int k = tid; k < 128; k += 64) {
        float s = g2[k] * rsqrtf(v2[k] + BN_EPS);
        cs[k] = s;
        ct[k] = b2[k] * s + beta2[k] - m2[k] * s;
    }
    if (tid < 16) lperm[tid] = perm[min((int)(blockIdx.x * 16 + tid), N - 1)];
    __syncthreads();

    const int lane = tid;
    const int q = lane >> 4, m = lane & 15;
    const int rowbase = blockIdx.x * 16;
    const int node = lperm[m];
    const int n = (rowbase + m < N) ? min(cnt[node], CAP) : 0;
    const int np = (n + 3) & ~3;
    const int* __restrict__ c = col + (size_t)node * CAP;

    float acc[KS][8];
#pragma unroll
    for (int i = 0; i < KS; ++i)
#pragma unroll
        for (int e = 0; e < 8; ++e) acc[i][e] = 0.f;

    int4 ci = *(const int4*)c;
    for (int p = 0; p < np; p += 4) {
        const int pn = min(p + 4, CAP - 4);
        int4 cn = *(const int4*)(c + pn);
        const unsigned short* r0 = hin + (size_t)ci.x * FIN + q * 8;
        const unsigned short* r1 = hin + (size_t)ci.y * FIN + q * 8;
        const unsigned short* r2 = hin + (size_t)ci.z * FIN + q * 8;
        const unsigned short* r3 = hin + (size_t)ci.w * FIN + q * 8;
        uint4 v0[KS], v1[KS], v2[KS], v3[KS];
#pragma unroll
        for (int i = 0; i < KS; ++i) v0[i] = *(const uint4*)(r0 + i * 32);
#pragma unroll
        for (int i = 0; i < KS; ++i) v1[i] = *(const uint4*)(r1 + i * 32);
#pragma unroll
        for (int i = 0; i < KS; ++i) v2[i] = *(const uint4*)(r2 + i * 32);
#pragma unroll
        for (int i = 0; i < KS; ++i) v3[i] = *(const uint4*)(r3 + i * 32);
#pragma unroll
        for (int i = 0; i < KS; ++i) addv(acc[i], v0[i]);
#pragma unroll
        for (int i = 0; i < KS; ++i) addv(acc[i], v1[i]);
#pragma unroll
        for (int i = 0; i < KS; ++i) addv(acc[i], v2[i]);
#pragma unroll
        for (int i = 0; i < KS; ++i) addv(acc[i], v3[i]);
        ci = cn;
    }

    const float di = dinv[node];
    bf16x8 af[KS];
#pragma unroll
    for (int i = 0; i < KS; ++i)
#pragma unroll
        for (int e = 0; e < 8; ++e) af[i][e] = (short)f2bf(acc[i][e] * di);

    // MFMA1: z2 = a2 @ w2
    f32x4 accm[NT1];
#pragma unroll
    for (int nt = 0; nt < NT1; ++nt) accm[nt] = (f32x4){0.f, 0.f, 0.f, 0.f};
    const bf16x8* __restrict__ wf2 = (const bf16x8*)w2f;
#pragma unroll
    for (int ks = 0; ks < KS; ++ks)
#pragma unroll
        for (int nt = 0; nt < NT1; ++nt)
            accm[nt] = __builtin_amdgcn_mfma_f32_16x16x32_bf16(af[ks], wf2[(ks * NT1 + nt) * 64 + lane], accm[nt], 0, 0, 0);

    // h2 = relu(bn2(z2)) -> per-wave LDS tile (C-layout rows -> A-frag reads)
    unsigned short* ot = otile;
#pragma unroll
    for (int nt = 0; nt < NT1; ++nt) {
        int cc = nt * 16 + m;
        float s = cs[cc], t = ct[cc];
#pragma unroll
        for (int r = 0; r < 4; ++r) {
            float z = fmaxf(accm[nt][r] * s + t, 0.f);
            ot[(q * 4 + r) * OST + cc] = f2bf(z);
        }
    }
    bf16x8 af2[KS];
#pragma unroll
    for (int ks = 0; ks < KS; ++ks)
        af2[ks] = *(const bf16x8*)&ot[m * OST + ks * 32 + q * 8];

    // MFMA2: t3 = h2 @ w3
    f32x4 acc2[NT2];
#pragma unroll
    for (int nt = 0; nt < NT2; ++nt) acc2[nt] = (f32x4){0.f, 0.f, 0.f, 0.f};
    const bf16x8* __restrict__ wf3 = (const bf16x8*)w3f;
#pragma unroll
    for (int ks = 0; ks < KS; ++ks)
#pragma unroll
        for (int nt = 0; nt < NT2; ++nt)
            acc2[nt] = __builtin_amdgcn_mfma_f32_16x16x32_bf16(af2[ks], wf3[(ks * NT2 + nt) * 64 + lane], acc2[nt], 0, 0, 0);

    float rs[4];
#pragma unroll
    for (int r = 0; r < 4; ++r) rs[r] = dinv[lperm[q * 4 + r]];
#pragma unroll
    for (int nt = 0; nt < NT2; ++nt) {
        int cc = nt * 16 + m;
#pragma unroll
        for (int r = 0; r < 4; ++r)
            ot[(q * 4 + r) * OST2 + cc] = f2bf(acc2[nt][r] * rs[r]);
    }
#pragma unroll
    for (int idx = lane; idx < 16 * 8; idx += 64) {
        int rrow = idx >> 3, cc = idx & 7;
        if (rowbase + rrow < N) {
            int gr = lperm[rrow];
            *(uint4*)(out + (size_t)gr * 64 + cc * 8) = *(const uint4*)&ot[rrow * OST2 + cc * 8];
        }
    }
}

// ---------------- layer 3 tail fused: out = log_softmax( relu(bn3(A_hat@t3 + b3)) @ w_out + b_out ) ----------------
__global__ __launch_bounds__(64) void agg_final(
    const unsigned short* __restrict__ hin,
    const int* __restrict__ col, const int* __restrict__ cnt, const float* __restrict__ dinv,
    const int* __restrict__ perm,
    const float* __restrict__ b3, const float* __restrict__ g3, const float* __restrict__ beta3,
    const float* __restrict__ m3, const float* __restrict__ v3,
    const float* __restrict__ w_out, const float* __restrict__ b_out,
    float* __restrict__ out, int N)
{
    __shared__ float S[64], T[64], sw[64 * 8], sb[8];
    __shared__ int lperm[16];
    const int tid = threadIdx.x;
    {
        float s = g3[tid] * rsqrtf(v3[tid] + BN_EPS);
        S[tid] = s;
        T[tid] = b3[tid] * s + beta3[tid] - m3[tid] * s;
    }
    if (tid < 8) sb[tid] = b_out[tid];
    for (int i = tid; i < 512; i += 64) sw[i] = w_out[i];
    if (tid < 16) lperm[tid] = perm[min((int)(blockIdx.x * 16 + tid), N - 1)];
    __syncthreads();

    const int lane = tid;
    const int q = lane >> 4, m = lane & 15;
    const int rowbase = blockIdx.x * 16;
    const int node = lperm[m];
    const int n = (rowbase + m < N) ? min(cnt[node], CAP) : 0;
    const int np = (n + 3) & ~3;
    const int* __restrict__ c = col + (size_t)node * CAP;

    float acc[2][8];
#pragma unroll
    for (int i = 0; i < 2; ++i)
#pragma unroll
        for (int e = 0; e < 8; ++e) acc[i][e] = 0.f;

    int4 ca = *(const int4*)c;
    int4 cb = *(const int4*)(c + 4);
    int p = 0;
    for (; p + 8 <= np; p += 8) {
        const int pn = min(p + 8, CAP - 8);
        int4 na = *(const int4*)(c + pn);
        int4 nb = *(const int4*)(c + pn + 4);
        const unsigned short* r0 = hin + (size_t)ca.x * 64 + q * 8;
        const unsigned short* r1 = hin + (size_t)ca.y * 64 + q * 8;
        const unsigned short* r2 = hin + (size_t)ca.z * 64 + q * 8;
        const unsigned short* r3 = hin + (size_t)ca.w * 64 + q * 8;
        const unsigned short* r4 = hin + (size_t)cb.x * 64 + q * 8;
        const unsigned short* r5 = hin + (size_t)cb.y * 64 + q * 8;
        const unsigned short* r6 = hin + (size_t)cb.z * 64 + q * 8;
        const unsigned short* r7 = hin + (size_t)cb.w * 64 + q * 8;
        uint4 v0a = *(const uint4*)r0, v0b = *(const uint4*)(r0 + 32);
        uint4 v1a = *(const uint4*)r1, v1b = *(const uint4*)(r1 + 32);
        uint4 v2a = *(const uint4*)r2, v2b = *(const uint4*)(r2 + 32);
        uint4 v3a = *(const uint4*)r3, v3b = *(const uint4*)(r3 + 32);
        uint4 v4a = *(const uint4*)r4, v4b = *(const uint4*)(r4 + 32);
        uint4 v5a = *(const uint4*)r5, v5b = *(const uint4*)(r5 + 32);
        uint4 v6a = *(const uint4*)r6, v6b = *(const uint4*)(r6 + 32);
        uint4 v7a = *(const uint4*)r7, v7b = *(const uint4*)(r7 + 32);
        addv(acc[0], v0a); addv(acc[1], v0b);
        addv(acc[0], v1a); addv(acc[1], v1b);
        addv(acc[0], v2a); addv(acc[1], v2b);
        addv(acc[0], v3a); addv(acc[1], v3b);
        addv(acc[0], v4a); addv(acc[1], v4b);
        addv(acc[0], v5a); addv(acc[1], v5b);
        addv(acc[0], v6a); addv(acc[1], v6b);
        addv(acc[0], v7a); addv(acc[1], v7b);
        ca = na; cb = nb;
    }
    if (p < np) {  // remaining 4 (sentinel-padded)
        const unsigned short* r0 = hin + (size_t)ca.x * 64 + q * 8;
        const unsigned short* r1 = hin + (size_t)ca.y * 64 + q * 8;
        const unsigned short* r2 = hin + (size_t)ca.z * 64 + q * 8;
        const unsigned short* r3 = hin + (size_t)ca.w * 64 + q * 8;
        uint4 v0a = *(const uint4*)r0, v0b = *(const uint4*)(r0 + 32);
        uint4 v1a = *(const uint4*)r1, v1b = *(const uint4*)(r1 + 32);
        uint4 v2a = *(const uint4*)r2, v2b = *(const uint4*)(r2 + 32);
        uint4 v3a = *(const uint4*)r3, v3b = *(const uint4*)(r3 + 32);
        addv(acc[0], v0a); addv(acc[1], v0b);
        addv(acc[0], v1a); addv(acc[1], v1b);
        addv(acc[0], v2a); addv(acc[1], v2b);
        addv(acc[0], v3a); addv(acc[1], v3b);
    }

    const float di = dinv[node];
    float lg[8];
#pragma unroll
    for (int cc = 0; cc < 8; ++cc) lg[cc] = 0.f;
#pragma unroll
    for (int i = 0; i < 2; ++i) {
        int fbase = i * 32 + q * 8;
#pragma unroll
        for (int j = 0; j < 8; ++j) {
            int f = fbase + j;
            float z = fmaxf((acc[i][j] * di) * S[f] + T[f], 0.f);
#pragma unroll
            for (int cc = 0; cc < 8; ++cc) lg[cc] += z * sw[f * 8 + cc];
        }
    }
#pragma unroll
    for (int cc = 0; cc < 8; ++cc) {
        lg[cc] += __shfl_xor(lg[cc], 16);
        lg[cc] += __shfl_xor(lg[cc], 32);
    }
    if (q == 0 && rowbase + m < N) {
#pragma unroll
        for (int cc = 0; cc < 8; ++cc) lg[cc] += sb[cc];
        float mx = lg[0];
#pragma unroll
        for (int cc = 1; cc < 8; ++cc) mx = fmaxf(mx, lg[cc]);
        float sum = 0.f;
#pragma unroll
        for (int cc = 0; cc < 8; ++cc) sum += expf(lg[cc] - mx);
        float lse = logf(sum) + mx;
        float4 o0 = {lg[0] - lse, lg[1] - lse, lg[2] - lse, lg[3] - lse};
        float4 o1 = {lg[4] - lse, lg[5] - lse, lg[6] - lse, lg[7] - lse};
        float4* op = (float4*)(out + (size_t)node * 8);
        op[0] = o0;
        op[1] = o1;
    }
}

extern "C" void kernel_launch(void* const* d_in, const int* in_sizes, int n_in,
                              void* d_out, int out_size, void* d_ws, size_t ws_size,
                              hipStream_t stream) {
    const float* x     = (const float*)d_in[0];
    const int*   ei    = (const int*)d_in[1];
    const float* w_in  = (const float*)d_in[2];
    const float* b_in  = (const float*)d_in[3];
    const float* w1    = (const float*)d_in[4];
    const float* b1    = (const float*)d_in[5];
    const float* w2    = (const float*)d_in[6];
    const float* b2    = (const float*)d_in[7];
    const float* w3    = (const float*)d_in[8];
    const float* b3    = (const float*)d_in[9];
    const float* w_o   = (const float*)d_in[10];
    const float* b_o   = (const float*)d_in[11];
    const float* g1    = (const float*)d_in[12];
    const float* be1   = (const float*)d_in[13];
    const float* m1    = (const float*)d_in[14];
    const float* v1    = (const float*)d_in[15];
    const float* g2    = (const float*)d_in[16];
    const float* be2   = (const float*)d_in[17];
    const float* m2    = (const float*)d_in[18];
    const float* v2    = (const float*)d_in[19];
    const float* g3    = (const float*)d_in[20];
    const float* be3   = (const float*)d_in[21];
    const float* m3    = (const float*)d_in[22];
    const float* v3    = (const float*)d_in[23];

    const int N = in_sizes[0] / 128;
    const int E = in_sizes[1] / 2;
    const int K = (N + (1 << BSH) - 1) >> BSH;

    char* p = (char*)d_ws;
    auto alloc = [&](size_t bytes) {
        void* r = (void*)p;
        p += (bytes + 255) & ~(size_t)255;
        return r;
    };
    int*            cnt  = (int*)alloc((size_t)N * 4);
    float*          dinv = (float*)alloc((size_t)N * 4);
    int*            zbuf = (int*)alloc(512 * 4);         // [0..255]=bcnt, [256..383]=dhist
    int*            doff = (int*)alloc(128 * 4);
    int*            perm = (int*)alloc((size_t)N * 4);
    int*            col  = (int*)alloc((size_t)N * CAP * 4);
    uint2*          bins = (uint2*)alloc((size_t)K * BCAP * 8);
    unsigned short* hbA  = (unsigned short*)alloc((size_t)(N + 1) * 128 * 2);
    unsigned short* hbB  = (unsigned short*)alloc((size_t)(N + 1) * 128 * 2);
    unsigned short* f_in = (unsigned short*)alloc(8192 * 2);
    unsigned short* f1   = (unsigned short*)alloc(8192 * 2);
    unsigned short* f2   = (unsigned short*)alloc(16384 * 2);
    unsigned short* f3   = (unsigned short*)alloc(8192 * 2);
    int* bcnt  = zbuf;
    int* dhist = zbuf + 256;

    const int gN  = (N + 255) / 256;
    const int gB1 = (E + 2047) / 2048;
    const int gM  = (N + 63) / 64;
    const int gW  = (N + 15) / 16;

    // graph build (bucketed placement) + degree sort (descending) + weight repack
    k_zero<<<2, 256, 0, stream>>>(zbuf, 512);
    k_bin<<<gB1, 256, 0, stream>>>(ei, E, K, bins, bcnt);
    k_place<<<K, 1024, 0, stream>>>(bins, bcnt, col, cnt, dinv, dhist, N);
    k_prefix<<<1, 64, 0, stream>>>(dhist, doff);
    k_scatter<<<gN, 256, 0, stream>>>(cnt, doff, perm, N);
    k_repack<<<160, 256, 0, stream>>>(w_in, w1, w2, w3, f_in, f1, f2, f3);
    k_zrow<<<1, 128, 0, stream>>>(hbA, hbB, N);

    // h0 = bf16( dinv * relu(x @ w_in + b_in) )                     [N,64]  -> hbA
    mfma_gemm0<<<gM, 256, 0, stream>>>(x, f_in, b_in, dinv, hbA, N);
    // h1 = bf16( dinv * relu(bn1( (A_hat@h0) @ w1 + b1 )) )         [N,128] -> hbB
    agg_mfma1<<<gW, 64, 0, stream>>>(hbA, f1, b1, g1, be1, m1, v1, col, cnt, dinv, perm, hbB, N);
    // t3 = bf16( dinv * ( relu(bn2((A_hat@h1)@w2+b2)) @ w3 ) )      [N,64]  -> hbA
    agg_mfma23<<<gW, 64, 0, stream>>>(hbB, f2, b2, g2, be2, m2, v2, f3, col, cnt, dinv, perm, hbA, N);
    // out = log_softmax( relu(bn3(A_hat@t3 + b3)) @ w_out + b_out ) [N,8]
    agg_final<<<gW, 64, 0, stream>>>(hbA, col, cnt, dinv, perm, b3, g3, be3, m3, v3, w_o, b_o, (float*)d_out, N);
}

// Round 3
// 296.730 us; speedup vs baseline: 1.3811x; 1.1883x over previous
//
#include <hip/hip_runtime.h>
#include <math.h>

#define BN_EPS 1e-5f
constexpr int CAP = 64;     // max neighbors/node incl self-loop; deg~Poisson(16), P(>63)~0
constexpr int BSH = 9;      // dst-bucket shift: 512 nodes / bucket
constexpr int BCAP = 10240; // entries per bucket (avg 8192, sd ~90; +22 sigma)

typedef __attribute__((ext_vector_type(8))) short bf16x8;
typedef __attribute__((ext_vector_type(4))) float f32x4;
typedef __attribute__((ext_vector_type(2))) float f32x2n;

// ---- bf16 helpers (round-to-nearest-even) ----
__device__ inline unsigned short f2bf(float f) {
    unsigned u = __float_as_uint(f);
    unsigned r = (u + 0x7fffu + ((u >> 16) & 1u)) >> 16;
    return (unsigned short)r;
}
__device__ inline float bf2f(unsigned short s) {
    return __uint_as_float((unsigned)s << 16);
}

// ---- fp8 e4m3 (OCP on gfx950) helpers, HW cvt ----
__device__ inline unsigned pk8(float f0, float f1, float f2, float f3) {
    int u = __builtin_amdgcn_cvt_pk_fp8_f32(f0, f1, 0, false);
    u = __builtin_amdgcn_cvt_pk_fp8_f32(f2, f3, u, true);
    return (unsigned)u;
}
__device__ inline void addq(float* a, unsigned u) {
    f32x2n lo = __builtin_amdgcn_cvt_pk_f32_fp8((int)u, false);
    f32x2n hi = __builtin_amdgcn_cvt_pk_f32_fp8((int)u, true);
    a[0] += lo.x; a[1] += lo.y; a[2] += hi.x; a[3] += hi.y;
}
// one fp8 row chunk (16 features): bytes 0-7 -> a0[0..7], bytes 8-15 -> a1[0..7]
__device__ inline void addv8(float* a0, float* a1, uint4 v) {
    addq(a0, v.x); addq(a0 + 4, v.y); addq(a1, v.z); addq(a1 + 4, v.w);
}

// ---------------- graph build: 2-phase dst-binned counting sort ----------------
__global__ __launch_bounds__(256) void k_zero(int* __restrict__ buf, int L) {
    int i = blockIdx.x * 256 + threadIdx.x;
    if (i < L) buf[i] = 0;
}

__global__ __launch_bounds__(256) void k_bin(const int* __restrict__ ei, int E, int K,
                                             uint2* __restrict__ bins, int* __restrict__ bcnt) {
    __shared__ int hist[256];
    __shared__ int lbase[256];
    const int tid = threadIdx.x;
    const int e0 = blockIdx.x * 2048;
    hist[tid] = 0;
    __syncthreads();

    int s[8], d[8];
    bool m[8];
#pragma unroll
    for (int i = 0; i < 8; ++i) {
        int e = e0 + i * 256 + tid;
        m[i] = e < E;
        s[i] = m[i] ? ei[e] : 0;
        d[i] = m[i] ? ei[E + e] : 0;
        if (m[i]) atomicAdd(&hist[d[i] >> BSH], 1);
    }
    __syncthreads();
    if (tid < K && hist[tid] > 0) lbase[tid] = atomicAdd(&bcnt[tid], hist[tid]);
    __syncthreads();
    hist[tid] = 0;
    __syncthreads();
#pragma unroll
    for (int i = 0; i < 8; ++i) {
        if (m[i]) {
            int b = d[i] >> BSH;
            int pos = lbase[b] + atomicAdd(&hist[b], 1);
            if (pos < BCAP) bins[(size_t)b * BCAP + pos] = make_uint2((unsigned)s[i], (unsigned)d[i]);
        }
    }
}

// 2-pass bucketed placement: neighbor lists grouped by src>>14 windows; pads each
// list to a multiple of 4 with sentinel id N (tables carry a zeroed row N).
__global__ __launch_bounds__(1024) void k_place(const uint2* __restrict__ bins,
                                                const int* __restrict__ bcnt,
                                                int* __restrict__ col, int* __restrict__ cnt,
                                                float* __restrict__ dinv, int* __restrict__ dhist,
                                                int N) {
    const int b = blockIdx.x;
    const int node0 = b << BSH;
    const int nn = min(1 << BSH, N - node0);
    __shared__ int c2[1 << BSH];
    __shared__ int bk[(1 << BSH) * 8];
    __shared__ int lh[CAP + 2];
    const int tid = threadIdx.x;
    if (tid < CAP + 2) lh[tid] = 0;
    for (int i = tid; i < nn * 8; i += 1024) bk[i] = 0;
    for (int i = tid; i < nn; i += 1024) col[(size_t)(node0 + i) * CAP] = node0 + i;
    __syncthreads();
    const int nb = min(bcnt[b], BCAP);
    const uint2* __restrict__ bb = bins + (size_t)b * BCAP;
    // pass 1: count per (dst, src-bucket)
    for (int i = tid; i < nb; i += 1024) {
        uint2 e = bb[i];
        int bu = min((int)(e.x >> 14), 7);
        atomicAdd(&bk[((int)e.y - node0) * 8 + bu], 1);
    }
    __syncthreads();
    // per-dst exclusive prefix (+1: self-loop at slot 0); bk becomes write cursors
    for (int i = tid; i < nn; i += 1024) {
        int s = 1;
#pragma unroll
        for (int u = 0; u < 8; ++u) { int t = bk[i * 8 + u]; bk[i * 8 + u] = s; s += t; }
        c2[i] = s;
    }
    __syncthreads();
    // pass 2: bucketed placement
    for (int i = tid; i < nb; i += 1024) {
        uint2 e = bb[i];
        int bu = min((int)(e.x >> 14), 7);
        int pos = atomicAdd(&bk[((int)e.y - node0) * 8 + bu], 1);
        if (pos < CAP) col[(size_t)e.y * CAP + pos] = (int)e.x;
    }
    __syncthreads();
    for (int i = tid; i < nn; i += 1024) {
        int c = c2[i];
        cnt[node0 + i] = c;
        dinv[node0 + i] = rsqrtf((float)c);
        int cc = min(c, CAP), c4 = (cc + 3) & ~3;
        for (int j = cc; j < c4; ++j) col[(size_t)(node0 + i) * CAP + j] = N;
        atomicAdd(&lh[min(c, CAP)], 1);
    }
    __syncthreads();
    if (tid <= CAP && lh[tid] > 0) atomicAdd(&dhist[tid], lh[tid]);
}

// zero the sentinel row N of both fp8 feature tables
__global__ void k_zrow(unsigned char* __restrict__ a, unsigned char* __restrict__ b, int N) {
    int t = threadIdx.x;  // 128
    if (t < 64) a[(size_t)N * 64 + t] = 0;
    b[(size_t)N * 128 + t] = 0;
}

// exclusive prefix over degree histogram, DESCENDING degree -> heavy blocks launch first
__global__ void k_prefix(const int* __restrict__ dhist, int* __restrict__ doff) {
    if (threadIdx.x == 0) {
        int s = 0;
        for (int b = CAP; b >= 0; --b) { doff[b] = s; s += dhist[b]; }
    }
}

// scatter node ids into degree-sorted permutation
__global__ __launch_bounds__(256) void k_scatter(const int* __restrict__ cnt, int* __restrict__ doff,
                                                 int* __restrict__ perm, int N) {
    __shared__ int lh[CAP + 2];
    __shared__ int lbase[CAP + 2];
    __shared__ int lpos[CAP + 2];
    const int tid = threadIdx.x;
    if (tid < CAP + 2) { lh[tid] = 0; lpos[tid] = 0; }
    __syncthreads();
    const int i = blockIdx.x * 256 + tid;
    const bool act = i < N;
    int b = 0;
    if (act) { b = min(cnt[i], CAP); atomicAdd(&lh[b], 1); }
    __syncthreads();
    if (tid <= CAP && lh[tid] > 0) lbase[tid] = atomicAdd(&doff[tid], lh[tid]);
    __syncthreads();
    if (act) {
        int p = atomicAdd(&lpos[b], 1);
        perm[lbase[b] + p] = i;
    }
}

// ---------------- weight repack: fp32 [FIN][FOUT] -> bf16 fragment-linear ----------------
__global__ __launch_bounds__(256) void k_repack(
    const float* __restrict__ w_in, const float* __restrict__ w1,
    const float* __restrict__ w2, const float* __restrict__ w3,
    unsigned short* __restrict__ f_in, unsigned short* __restrict__ f1,
    unsigned short* __restrict__ f2, unsigned short* __restrict__ f3)
{
    int idx = blockIdx.x * 256 + threadIdx.x;  // 0..40959
    const float* src;
    unsigned short* dst;
    int FOUT, local;
    if (idx < 8192)       { src = w_in; dst = f_in; FOUT = 64;  local = idx; }
    else if (idx < 16384) { src = w1;   dst = f1;   FOUT = 128; local = idx - 8192; }
    else if (idx < 32768) { src = w2;   dst = f2;   FOUT = 128; local = idx - 16384; }
    else                  { src = w3;   dst = f3;   FOUT = 64;  local = idx - 32768; }
    int k = local / FOUT, n = local % FOUT;
    int NT = FOUT >> 4;
    dst[((((k >> 5) * NT + (n >> 4)) * 64) + ((k >> 3) & 3) * 16 + (n & 15)) * 8 + (k & 7)] = f2bf(src[local]);
}

// ---------------- layer 0: h0 = fp8( dinv * relu(x @ w_in + b_in) ) ----------------
// Output: fp8 frag-permuted 64B rows: byte chunk j*16 holds features {j*8..j*8+7, 32+j*8..32+j*8+7}
__global__ __launch_bounds__(256) void mfma_gemm0(
    const float* __restrict__ in, const unsigned short* __restrict__ wfrag,
    const float* __restrict__ bias, const float* __restrict__ rowscale,
    unsigned char* __restrict__ out, int N)
{
    constexpr int FIN = 128, FOUT = 64, KS = 4, NT = 4, OST = 72;
    __shared__ unsigned short otile[4 * 16 * OST];
    __shared__ float ct[FOUT];
    const int tid = threadIdx.x;
    if (tid < FOUT) ct[tid] = bias[tid];
    __syncthreads();

    const int wid = tid >> 6, lane = tid & 63;
    const int q = lane >> 4, m = lane & 15;
    const int rowbase = blockIdx.x * 64 + wid * 16;
    const int rowc = min(rowbase + m, N - 1);
    const bf16x8* __restrict__ wf = (const bf16x8*)wfrag;

    f32x4 accm[NT];
#pragma unroll
    for (int nt = 0; nt < NT; ++nt) accm[nt] = (f32x4){0.f, 0.f, 0.f, 0.f};

#pragma unroll
    for (int ks = 0; ks < KS; ++ks) {
        const float* ap = in + (size_t)rowc * FIN + ks * 32 + q * 8;
        float4 a0 = *(const float4*)ap;
        float4 a1 = *(const float4*)(ap + 4);
        bf16x8 af;
        af[0] = (short)f2bf(a0.x); af[1] = (short)f2bf(a0.y);
        af[2] = (short)f2bf(a0.z); af[3] = (short)f2bf(a0.w);
        af[4] = (short)f2bf(a1.x); af[5] = (short)f2bf(a1.y);
        af[6] = (short)f2bf(a1.z); af[7] = (short)f2bf(a1.w);
#pragma unroll
        for (int nt = 0; nt < NT; ++nt)
            accm[nt] = __builtin_amdgcn_mfma_f32_16x16x32_bf16(af, wf[(ks * NT + nt) * 64 + lane], accm[nt], 0, 0, 0);
    }

    unsigned short* ot = otile + wid * 16 * OST;
    float rs[4];
#pragma unroll
    for (int r = 0; r < 4; ++r) rs[r] = rowscale[min(rowbase + q * 4 + r, N - 1)];
#pragma unroll
    for (int nt = 0; nt < NT; ++nt) {
        int c = nt * 16 + m;
        float t = ct[c];
#pragma unroll
        for (int r = 0; r < 4; ++r) {
            float z = fmaxf(accm[nt][r] + t, 0.f);
            ot[(q * 4 + r) * OST + c] = f2bf(z * rs[r]);
        }
    }
    {
        int rrow = lane >> 2, j = lane & 3;
        int gr = rowbase + rrow;
        if (gr < N) {
            const unsigned short* rp = &ot[rrow * OST + j * 8];
            uint4 u;
            u.x = pk8(bf2f(rp[0]),  bf2f(rp[1]),  bf2f(rp[2]),  bf2f(rp[3]));
            u.y = pk8(bf2f(rp[4]),  bf2f(rp[5]),  bf2f(rp[6]),  bf2f(rp[7]));
            u.z = pk8(bf2f(rp[32]), bf2f(rp[33]), bf2f(rp[34]), bf2f(rp[35]));
            u.w = pk8(bf2f(rp[36]), bf2f(rp[37]), bf2f(rp[38]), bf2f(rp[39]));
            *(uint4*)(out + (size_t)gr * 64 + j * 16) = u;
        }
    }
}

// ---------------- layer 1: h1 = fp8( dinv * relu(bn1( (A_hat@h0) @ w1 + b1 )) ) ----------------
// Gathers fp8 64B rows (1 line-request/row), single-wave blocks, 8-neighbor batches.
__global__ __launch_bounds__(64) void agg_mfma1(
    const unsigned char* __restrict__ hin, const unsigned short* __restrict__ wfrag,
    const float* __restrict__ bias, const float* __restrict__ g, const float* __restrict__ beta,
    const float* __restrict__ mm, const float* __restrict__ vv,
    const int* __restrict__ col, const int* __restrict__ cnt, const float* __restrict__ dinv,
    const int* __restrict__ perm,
    unsigned char* __restrict__ out, int N)
{
    constexpr int FOUT = 128, KS = 2, NT = 8, OST = 136;
    __shared__ unsigned short otile[16 * OST];
    __shared__ float cs[FOUT], ct[FOUT];
    __shared__ int lperm[16];
    const int tid = threadIdx.x;
    for (int k = tid; k < FOUT; k += 64) {
        float s = g[k] * rsqrtf(vv[k] + BN_EPS);
        cs[k] = s;
        ct[k] = bias[k] * s + beta[k] - mm[k] * s;
    }
    if (tid < 16) lperm[tid] = perm[min((int)(blockIdx.x * 16 + tid), N - 1)];
    __syncthreads();

    const int lane = tid;
    const int q = lane >> 4, m = lane & 15;
    const int rowbase = blockIdx.x * 16;
    const int node = lperm[m];
    const int n = (rowbase + m < N) ? min(cnt[node], CAP) : 0;
    const int np = (n + 3) & ~3;
    const int* __restrict__ c = col + (size_t)node * CAP;
    const int qo = q << 4;

    float acc[KS][8];
#pragma unroll
    for (int i = 0; i < KS; ++i)
#pragma unroll
        for (int e = 0; e < 8; ++e) acc[i][e] = 0.f;

    int4 ca = *(const int4*)c;
    int4 cb = *(const int4*)(c + 4);
    int p = 0;
    for (; p + 8 <= np; p += 8) {
        const int pn = min(p + 8, CAP - 8);
        int4 na = *(const int4*)(c + pn);
        int4 nb = *(const int4*)(c + pn + 4);
        uint4 v0 = *(const uint4*)(hin + (size_t)ca.x * 64 + qo);
        uint4 v1 = *(const uint4*)(hin + (size_t)ca.y * 64 + qo);
        uint4 v2 = *(const uint4*)(hin + (size_t)ca.z * 64 + qo);
        uint4 v3 = *(const uint4*)(hin + (size_t)ca.w * 64 + qo);
        uint4 v4 = *(const uint4*)(hin + (size_t)cb.x * 64 + qo);
        uint4 v5 = *(const uint4*)(hin + (size_t)cb.y * 64 + qo);
        uint4 v6 = *(const uint4*)(hin + (size_t)cb.z * 64 + qo);
        uint4 v7 = *(const uint4*)(hin + (size_t)cb.w * 64 + qo);
        addv8(acc[0], acc[1], v0);
        addv8(acc[0], acc[1], v1);
        addv8(acc[0], acc[1], v2);
        addv8(acc[0], acc[1], v3);
        addv8(acc[0], acc[1], v4);
        addv8(acc[0], acc[1], v5);
        addv8(acc[0], acc[1], v6);
        addv8(acc[0], acc[1], v7);
        ca = na; cb = nb;
    }
    if (p < np) {  // remaining 4 (sentinel-padded)
        uint4 v0 = *(const uint4*)(hin + (size_t)ca.x * 64 + qo);
        uint4 v1 = *(const uint4*)(hin + (size_t)ca.y * 64 + qo);
        uint4 v2 = *(const uint4*)(hin + (size_t)ca.z * 64 + qo);
        uint4 v3 = *(const uint4*)(hin + (size_t)ca.w * 64 + qo);
        addv8(acc[0], acc[1], v0);
        addv8(acc[0], acc[1], v1);
        addv8(acc[0], acc[1], v2);
        addv8(acc[0], acc[1], v3);
    }

    const float di = dinv[node];
    bf16x8 af[KS];
#pragma unroll
    for (int i = 0; i < KS; ++i)
#pragma unroll
        for (int e = 0; e < 8; ++e) af[i][e] = (short)f2bf(acc[i][e] * di);

    f32x4 accm[NT];
#pragma unroll
    for (int nt = 0; nt < NT; ++nt) accm[nt] = (f32x4){0.f, 0.f, 0.f, 0.f};
    const bf16x8* __restrict__ wf = (const bf16x8*)wfrag;
#pragma unroll
    for (int ks = 0; ks < KS; ++ks)
#pragma unroll
        for (int nt = 0; nt < NT; ++nt)
            accm[nt] = __builtin_amdgcn_mfma_f32_16x16x32_bf16(af[ks], wf[(ks * NT + nt) * 64 + lane], accm[nt], 0, 0, 0);

    unsigned short* ot = otile;
    float rs[4];
#pragma unroll
    for (int r = 0; r < 4; ++r) rs[r] = dinv[lperm[q * 4 + r]];
#pragma unroll
    for (int nt = 0; nt < NT; ++nt) {
        int cc = nt * 16 + m;
        float s = cs[cc], t = ct[cc];
#pragma unroll
        for (int r = 0; r < 4; ++r) {
            float z = fmaxf(accm[nt][r] * s + t, 0.f);
            ot[(q * 4 + r) * OST + cc] = f2bf(z * rs[r]);
        }
    }
    // writer: fp8 frag-permuted 128B rows: chunk (hi,qq) at byte hi*64+qq*16 holds
    // features {hi*64+qq*8..+7, hi*64+32+qq*8..+7}
#pragma unroll
    for (int idx = lane; idx < 128; idx += 64) {
        int rrow = idx >> 3, c8 = idx & 7;
        int hi = c8 >> 2, qq = c8 & 3;
        if (rowbase + rrow < N) {
            int gr = lperm[rrow];
            const unsigned short* rp = &ot[rrow * OST + hi * 64 + qq * 8];
            uint4 u;
            u.x = pk8(bf2f(rp[0]),  bf2f(rp[1]),  bf2f(rp[2]),  bf2f(rp[3]));
            u.y = pk8(bf2f(rp[4]),  bf2f(rp[5]),  bf2f(rp[6]),  bf2f(rp[7]));
            u.z = pk8(bf2f(rp[32]), bf2f(rp[33]), bf2f(rp[34]), bf2f(rp[35]));
            u.w = pk8(bf2f(rp[36]), bf2f(rp[37]), bf2f(rp[38]), bf2f(rp[39]));
            *(uint4*)(out + (size_t)gr * 128 + hi * 64 + qq * 16) = u;
        }
    }
}

// ---------------- layers 2+3 fused: t3 = fp8( dinv * ( relu(bn2((A_hat@h1)@w2+b2)) @ w3 ) ) ----------------
// Gathers fp8 128B rows (2 line-requests/row), 8-neighbor batches.
__global__ __launch_bounds__(64) void agg_mfma23(
    const unsigned char* __restrict__ hin, const unsigned short* __restrict__ w2f,
    const float* __restrict__ b2, const float* __restrict__ g2, const float* __restrict__ beta2,
    const float* __restrict__ m2, const float* __restrict__ v2,
    const unsigned short* __restrict__ w3f,
    const int* __restrict__ col, const int* __restrict__ cnt, const float* __restrict__ dinv,
    const int* __restrict__ perm,
    unsigned char* __restrict__ out, int N)
{
    constexpr int KS = 4, NT1 = 8, NT2 = 4, OST = 136, OST2 = 72;
    __shared__ unsigned short otile[16 * OST];
    __shared__ float cs[128], ct[128];
    __shared__ int lperm[16];
    const int tid = threadIdx.x;
    for (int k = tid; k < 128; k += 64) {
        float s = g2[k] * rsqrtf(v2[k] + BN_EPS);
        cs[k] = s;
        ct[k] = b2[k] * s + beta2[k] - m2[k] * s;
    }
    if (tid < 16) lperm[tid] = perm[min((int)(blockIdx.x * 16 + tid), N - 1)];
    __syncthreads();

    const int lane = tid;
    const int q = lane >> 4, m = lane & 15;
    const int rowbase = blockIdx.x * 16;
    const int node = lperm[m];
    const int n = (rowbase + m < N) ? min(cnt[node], CAP) : 0;
    const int np = (n + 3) & ~3;
    const int* __restrict__ c = col + (size_t)node * CAP;
    const int qo = q << 4;

    float acc[KS][8];
#pragma unroll
    for (int i = 0; i < KS; ++i)
#pragma unroll
        for (int e = 0; e < 8; ++e) acc[i][e] = 0.f;

    int4 ca = *(const int4*)c;
    int4 cb = *(const int4*)(c + 4);
    int p = 0;
    for (; p + 8 <= np; p += 8) {
        const int pn = min(p + 8, CAP - 8);
        int4 na = *(const int4*)(c + pn);
        int4 nb = *(const int4*)(c + pn + 4);
        const unsigned char* r0 = hin + (size_t)ca.x * 128 + qo;
        const unsigned char* r1 = hin + (size_t)ca.y * 128 + qo;
        const unsigned char* r2 = hin + (size_t)ca.z * 128 + qo;
        const unsigned char* r3 = hin + (size_t)ca.w * 128 + qo;
        const unsigned char* r4 = hin + (size_t)cb.x * 128 + qo;
        const unsigned char* r5 = hin + (size_t)cb.y * 128 + qo;
        const unsigned char* r6 = hin + (size_t)cb.z * 128 + qo;
        const unsigned char* r7 = hin + (size_t)cb.w * 128 + qo;
        uint4 a0 = *(const uint4*)r0, b0 = *(const uint4*)(r0 + 64);
        uint4 a1 = *(const uint4*)r1, b1 = *(const uint4*)(r1 + 64);
        uint4 a2 = *(const uint4*)r2, b2v = *(const uint4*)(r2 + 64);
        uint4 a3 = *(const uint4*)r3, b3v = *(const uint4*)(r3 + 64);
        uint4 a4 = *(const uint4*)r4, b4 = *(const uint4*)(r4 + 64);
        uint4 a5 = *(const uint4*)r5, b5 = *(const uint4*)(r5 + 64);
        uint4 a6 = *(const uint4*)r6, b6 = *(const uint4*)(r6 + 64);
        uint4 a7 = *(const uint4*)r7, b7 = *(const uint4*)(r7 + 64);
        addv8(acc[0], acc[1], a0); addv8(acc[2], acc[3], b0);
        addv8(acc[0], acc[1], a1); addv8(acc[2], acc[3], b1);
        addv8(acc[0], acc[1], a2); addv8(acc[2], acc[3], b2v);
        addv8(acc[0], acc[1], a3); addv8(acc[2], acc[3], b3v);
        addv8(acc[0], acc[1], a4); addv8(acc[2], acc[3], b4);
        addv8(acc[0], acc[1], a5); addv8(acc[2], acc[3], b5);
        addv8(acc[0], acc[1], a6); addv8(acc[2], acc[3], b6);
        addv8(acc[0], acc[1], a7); addv8(acc[2], acc[3], b7);
        ca = na; cb = nb;
    }
    if (p < np) {  // remaining 4 (sentinel-padded)
        const unsigned char* r0 = hin + (size_t)ca.x * 128 + qo;
        const unsigned char* r1 = hin + (size_t)ca.y * 128 + qo;
        const unsigned char* r2 = hin + (size_t)ca.z * 128 + qo;
        const unsigned char* r3 = hin + (size_t)ca.w * 128 + qo;
        uint4 a0 = *(const uint4*)r0, b0 = *(const uint4*)(r0 + 64);
        uint4 a1 = *(const uint4*)r1, b1 = *(const uint4*)(r1 + 64);
        uint4 a2 = *(const uint4*)r2, b2v = *(const uint4*)(r2 + 64);
        uint4 a3 = *(const uint4*)r3, b3v = *(const uint4*)(r3 + 64);
        addv8(acc[0], acc[1], a0); addv8(acc[2], acc[3], b0);
        addv8(acc[0], acc[1], a1); addv8(acc[2], acc[3], b1);
        addv8(acc[0], acc[1], a2); addv8(acc[2], acc[3], b2v);
        addv8(acc[0], acc[1], a3); addv8(acc[2], acc[3], b3v);
    }

    const float di = dinv[node];
    bf16x8 af[KS];
#pragma unroll
    for (int i = 0; i < KS; ++i)
#pragma unroll
        for (int e = 0; e < 8; ++e) af[i][e] = (short)f2bf(acc[i][e] * di);

    // MFMA1: z2 = a2 @ w2
    f32x4 accm[NT1];
#pragma unroll
    for (int nt = 0; nt < NT1; ++nt) accm[nt] = (f32x4){0.f, 0.f, 0.f, 0.f};
    const bf16x8* __restrict__ wf2 = (const bf16x8*)w2f;
#pragma unroll
    for (int ks = 0; ks < KS; ++ks)
#pragma unroll
        for (int nt = 0; nt < NT1; ++nt)
            accm[nt] = __builtin_amdgcn_mfma_f32_16x16x32_bf16(af[ks], wf2[(ks * NT1 + nt) * 64 + lane], accm[nt], 0, 0, 0);

    // h2 = relu(bn2(z2)) -> per-wave LDS tile (C-layout rows -> A-frag reads)
    unsigned short* ot = otile;
#pragma unroll
    for (int nt = 0; nt < NT1; ++nt) {
        int cc = nt * 16 + m;
        float s = cs[cc], t = ct[cc];
#pragma unroll
        for (int r = 0; r < 4; ++r) {
            float z = fmaxf(accm[nt][r] * s + t, 0.f);
            ot[(q * 4 + r) * OST + cc] = f2bf(z);
        }
    }
    bf16x8 af2[KS];
#pragma unroll
    for (int ks = 0; ks < KS; ++ks)
        af2[ks] = *(const bf16x8*)&ot[m * OST + ks * 32 + q * 8];

    // MFMA2: t3 = h2 @ w3
    f32x4 acc2[NT2];
#pragma unroll
    for (int nt = 0; nt < NT2; ++nt) acc2[nt] = (f32x4){0.f, 0.f, 0.f, 0.f};
    const bf16x8* __restrict__ wf3 = (const bf16x8*)w3f;
#pragma unroll
    for (int ks = 0; ks < KS; ++ks)
#pragma unroll
        for (int nt = 0; nt < NT2; ++nt)
            acc2[nt] = __builtin_amdgcn_mfma_f32_16x16x32_bf16(af2[ks], wf3[(ks * NT2 + nt) * 64 + lane], acc2[nt], 0, 0, 0);

    float rs[4];
#pragma unroll
    for (int r = 0; r < 4; ++r) rs[r] = dinv[lperm[q * 4 + r]];
#pragma unroll
    for (int nt = 0; nt < NT2; ++nt) {
        int cc = nt * 16 + m;
#pragma unroll
        for (int r = 0; r < 4; ++r)
            ot[(q * 4 + r) * OST2 + cc] = f2bf(acc2[nt][r] * rs[r]);
    }
    // writer: fp8 frag-permuted 64B rows
    {
        int rrow = lane >> 2, j = lane & 3;
        if (rowbase + rrow < N) {
            int gr = lperm[rrow];
            const unsigned short* rp = &ot[rrow * OST2 + j * 8];
            uint4 u;
            u.x = pk8(bf2f(rp[0]),  bf2f(rp[1]),  bf2f(rp[2]),  bf2f(rp[3]));
            u.y = pk8(bf2f(rp[4]),  bf2f(rp[5]),  bf2f(rp[6]),  bf2f(rp[7]));
            u.z = pk8(bf2f(rp[32]), bf2f(rp[33]), bf2f(rp[34]), bf2f(rp[35]));
            u.w = pk8(bf2f(rp[36]), bf2f(rp[37]), bf2f(rp[38]), bf2f(rp[39]));
            *(uint4*)(out + (size_t)gr * 64 + j * 16) = u;
        }
    }
}

// ---------------- layer 3 tail fused: out = log_softmax( relu(bn3(A_hat@t3 + b3)) @ w_out + b_out ) ----------------
__global__ __launch_bounds__(64) void agg_final(
    const unsigned char* __restrict__ hin,
    const int* __restrict__ col, const int* __restrict__ cnt, const float* __restrict__ dinv,
    const int* __restrict__ perm,
    const float* __restrict__ b3, const float* __restrict__ g3, const float* __restrict__ beta3,
    const float* __restrict__ m3, const float* __restrict__ v3,
    const float* __restrict__ w_out, const float* __restrict__ b_out,
    float* __restrict__ out, int N)
{
    __shared__ float S[64], T[64], sw[64 * 8], sb[8];
    __shared__ int lperm[16];
    const int tid = threadIdx.x;
    {
        float s = g3[tid] * rsqrtf(v3[tid] + BN_EPS);
        S[tid] = s;
        T[tid] = b3[tid] * s + beta3[tid] - m3[tid] * s;
    }
    if (tid < 8) sb[tid] = b_out[tid];
    for (int i = tid; i < 512; i += 64) sw[i] = w_out[i];
    if (tid < 16) lperm[tid] = perm[min((int)(blockIdx.x * 16 + tid), N - 1)];
    __syncthreads();

    const int lane = tid;
    const int q = lane >> 4, m = lane & 15;
    const int rowbase = blockIdx.x * 16;
    const int node = lperm[m];
    const int n = (rowbase + m < N) ? min(cnt[node], CAP) : 0;
    const int np = (n + 3) & ~3;
    const int* __restrict__ c = col + (size_t)node * CAP;
    const int qo = q << 4;

    float acc[2][8];
#pragma unroll
    for (int i = 0; i < 2; ++i)
#pragma unroll
        for (int e = 0; e < 8; ++e) acc[i][e] = 0.f;

    int4 ca = *(const int4*)c;
    int4 cb = *(const int4*)(c + 4);
    int p = 0;
    for (; p + 8 <= np; p += 8) {
        const int pn = min(p + 8, CAP - 8);
        int4 na = *(const int4*)(c + pn);
        int4 nb = *(const int4*)(c + pn + 4);
        uint4 v0 = *(const uint4*)(hin + (size_t)ca.x * 64 + qo);
        uint4 v1 = *(const uint4*)(hin + (size_t)ca.y * 64 + qo);
        uint4 v2 = *(const uint4*)(hin + (size_t)ca.z * 64 + qo);
        uint4 v3 = *(const uint4*)(hin + (size_t)ca.w * 64 + qo);
        uint4 v4 = *(const uint4*)(hin + (size_t)cb.x * 64 + qo);
        uint4 v5 = *(const uint4*)(hin + (size_t)cb.y * 64 + qo);
        uint4 v6 = *(const uint4*)(hin + (size_t)cb.z * 64 + qo);
        uint4 v7 = *(const uint4*)(hin + (size_t)cb.w * 64 + qo);
        addv8(acc[0], acc[1], v0);
        addv8(acc[0], acc[1], v1);
        addv8(acc[0], acc[1], v2);
        addv8(acc[0], acc[1], v3);
        addv8(acc[0], acc[1], v4);
        addv8(acc[0], acc[1], v5);
        addv8(acc[0], acc[1], v6);
        addv8(acc[0], acc[1], v7);
        ca = na; cb = nb;
    }
    if (p < np) {  // remaining 4 (sentinel-padded)
        uint4 v0 = *(const uint4*)(hin + (size_t)ca.x * 64 + qo);
        uint4 v1 = *(const uint4*)(hin + (size_t)ca.y * 64 + qo);
        uint4 v2 = *(const uint4*)(hin + (size_t)ca.z * 64 + qo);
        uint4 v3 = *(const uint4*)(hin + (size_t)ca.w * 64 + qo);
        addv8(acc[0], acc[1], v0);
        addv8(acc[0], acc[1], v1);
        addv8(acc[0], acc[1], v2);
        addv8(acc[0], acc[1], v3);
    }

    const float di = dinv[node];
    float lg[8];
#pragma unroll
    for (int cc = 0; cc < 8; ++cc) lg[cc] = 0.f;
#pragma unroll
    for (int i = 0; i < 2; ++i) {
        int fbase = i * 32 + q * 8;
#pragma unroll
        for (int j = 0; j < 8; ++j) {
            int f = fbase + j;
            float z = fmaxf((acc[i][j] * di) * S[f] + T[f], 0.f);
#pragma unroll
            for (int cc = 0; cc < 8; ++cc) lg[cc] += z * sw[f * 8 + cc];
        }
    }
#pragma unroll
    for (int cc = 0; cc < 8; ++cc) {
        lg[cc] += __shfl_xor(lg[cc], 16);
        lg[cc] += __shfl_xor(lg[cc], 32);
    }
    if (q == 0 && rowbase + m < N) {
#pragma unroll
        for (int cc = 0; cc < 8; ++cc) lg[cc] += sb[cc];
        float mx = lg[0];
#pragma unroll
        for (int cc = 1; cc < 8; ++cc) mx = fmaxf(mx, lg[cc]);
        float sum = 0.f;
#pragma unroll
        for (int cc = 0; cc < 8; ++cc) sum += expf(lg[cc] - mx);
        float lse = logf(sum) + mx;
        float4 o0 = {lg[0] - lse, lg[1] - lse, lg[2] - lse, lg[3] - lse};
        float4 o1 = {lg[4] - lse, lg[5] - lse, lg[6] - lse, lg[7] - lse};
        float4* op = (float4*)(out + (size_t)node * 8);
        op[0] = o0;
        op[1] = o1;
    }
}

extern "C" void kernel_launch(void* const* d_in, const int* in_sizes, int n_in,
                              void* d_out, int out_size, void* d_ws, size_t ws_size,
                              hipStream_t stream) {
    const float* x     = (const float*)d_in[0];
    const int*   ei    = (const int*)d_in[1];
    const float* w_in  = (const float*)d_in[2];
    const float* b_in  = (const float*)d_in[3];
    const float* w1    = (const float*)d_in[4];
    const float* b1    = (const float*)d_in[5];
    const float* w2    = (const float*)d_in[6];
    const float* b2    = (const float*)d_in[7];
    const float* w3    = (const float*)d_in[8];
    const float* b3    = (const float*)d_in[9];
    const float* w_o   = (const float*)d_in[10];
    const float* b_o   = (const float*)d_in[11];
    const float* g1    = (const float*)d_in[12];
    const float* be1   = (const float*)d_in[13];
    const float* m1    = (const float*)d_in[14];
    const float* v1    = (const float*)d_in[15];
    const float* g2    = (const float*)d_in[16];
    const float* be2   = (const float*)d_in[17];
    const float* m2    = (const float*)d_in[18];
    const float* v2    = (const float*)d_in[19];
    const float* g3    = (const float*)d_in[20];
    const float* be3   = (const float*)d_in[21];
    const float* m3    = (const float*)d_in[22];
    const float* v3    = (const float*)d_in[23];

    const int N = in_sizes[0] / 128;
    const int E = in_sizes[1] / 2;
    const int K = (N + (1 << BSH) - 1) >> BSH;

    char* p = (char*)d_ws;
    auto alloc = [&](size_t bytes) {
        void* r = (void*)p;
        p += (bytes + 255) & ~(size_t)255;
        return r;
    };
    int*            cnt  = (int*)alloc((size_t)N * 4);
    float*          dinv = (float*)alloc((size_t)N * 4);
    int*            zbuf = (int*)alloc(512 * 4);         // [0..255]=bcnt, [256..383]=dhist
    int*            doff = (int*)alloc(128 * 4);
    int*            perm = (int*)alloc((size_t)N * 4);
    int*            col  = (int*)alloc((size_t)N * CAP * 4);
    uint2*          bins = (uint2*)alloc((size_t)K * BCAP * 8);
    unsigned char*  hbA8 = (unsigned char*)alloc((size_t)(N + 1) * 64);   // h0 then t3 (fp8)
    unsigned char*  hbB8 = (unsigned char*)alloc((size_t)(N + 1) * 128);  // h1 (fp8)
    unsigned short* f_in = (unsigned short*)alloc(8192 * 2);
    unsigned short* f1   = (unsigned short*)alloc(8192 * 2);
    unsigned short* f2   = (unsigned short*)alloc(16384 * 2);
    unsigned short* f3   = (unsigned short*)alloc(8192 * 2);
    int* bcnt  = zbuf;
    int* dhist = zbuf + 256;

    const int gN  = (N + 255) / 256;
    const int gB1 = (E + 2047) / 2048;
    const int gM  = (N + 63) / 64;
    const int gW  = (N + 15) / 16;

    // graph build (bucketed placement) + degree sort (descending) + weight repack
    k_zero<<<2, 256, 0, stream>>>(zbuf, 512);
    k_bin<<<gB1, 256, 0, stream>>>(ei, E, K, bins, bcnt);
    k_place<<<K, 1024, 0, stream>>>(bins, bcnt, col, cnt, dinv, dhist, N);
    k_prefix<<<1, 64, 0, stream>>>(dhist, doff);
    k_scatter<<<gN, 256, 0, stream>>>(cnt, doff, perm, N);
    k_repack<<<160, 256, 0, stream>>>(w_in, w1, w2, w3, f_in, f1, f2, f3);
    k_zrow<<<1, 128, 0, stream>>>(hbA8, hbB8, N);

    // h0 = fp8( dinv * relu(x @ w_in + b_in) )                      [N,64]  -> hbA8
    mfma_gemm0<<<gM, 256, 0, stream>>>(x, f_in, b_in, dinv, hbA8, N);
    // h1 = fp8( dinv * relu(bn1( (A_hat@h0) @ w1 + b1 )) )          [N,128] -> hbB8
    agg_mfma1<<<gW, 64, 0, stream>>>(hbA8, f1, b1, g1, be1, m1, v1, col, cnt, dinv, perm, hbB8, N);
    // t3 = fp8( dinv * ( relu(bn2((A_hat@h1)@w2+b2)) @ w3 ) )       [N,64]  -> hbA8
    agg_mfma23<<<gW, 64, 0, stream>>>(hbB8, f2, b2, g2, be2, m2, v2, f3, col, cnt, dinv, perm, hbA8, N);
    // out = log_softmax( relu(bn3(A_hat@t3 + b3)) @ w_out + b_out ) [N,8]
    agg_final<<<gW, 64, 0, stream>>>(hbA8, col, cnt, dinv, perm, b3, g3, be3, m3, v3, w_o, b_o, (float*)d_out, N);
}